// Round 14
// baseline (298.979 us; speedup 1.0000x reference)
//
#include <hip/hip_runtime.h>
#include <stdint.h>

#pragma clang fp contract(off)

#define NB 4
#define NN 8192
#define NC 3
#define NG 12
#define MAXN 500
#define KEEP_CAP 512

typedef unsigned long long u64;
typedef uint32_t u32;
typedef uint16_t u16;

// ---------- ws layout (bytes) ----------
#define NSO   0u          // u32 [12][8192] sorted->orig
#define NSKEY 393216u     // u32 [12][8192] sorted key32
#define NSB4  786432u     // float4 [12][8192]
#define NSAR  2359296u    // f32 [12][8192]
#define NVAL  2752512u    // u64 [12][128] valid bits
#define NALV  2764800u    // u64 [12][128] keep bits
#define NKKEY 2777088u    // u32 [12][512]
#define NKPOS 2801664u    // u32 [12][512]
#define NKCNT 2826240u    // u32 [12]
#define NFLG  2826304u    // u32 [12] early-path flags
#define PMAT  3145728u    // u64 [12][32][2048] prefix matrix (6 MB), TRANSPOSED
#define NMAT  9437184u    // full matrices start
#define MATB  8388608ull  // 8192*128*8 per problem

// prefix-NMS parameters
#define PR_CH   32        // 32 chunks of 64 = 2048 rows
#define PR_ROWS 2048
#define PUNITS_PER_G 528  // sum_{rb=0}^{31}(32-rb)
#define PB_TPB 256
#define PB_BLOCKS 1584    // 6336 waves = 12*528 units, 1/wave

// ---------- old-path (fallback) ws layout ----------
#define WS_SORTED_ORIG 0
#define WS_ALIVE       393216
#define WS_KEPT_KEY    405504
#define WS_KEPT_POS    430080
#define WS_KEPT_CNT    454656
#define NMS_EPS 1.0000004f

__device__ __forceinline__ u32 sort_key(float s) {
  u32 b = __float_as_uint(s);
  u32 o = (b & 0x80000000u) ? ~b : (b | 0x80000000u);
  return ~o;   // ascending key == descending float; -inf -> 0xFF800000
}

// ================= sort (unchanged r6) =================
#define PHYS(i) ((i) + ((i) >> 3))
#define CEX(A, B, UP) \
  { if ((x[A] > x[B]) == (UP)) { u64 tt = x[A]; x[A] = x[B]; x[B] = tt; } }

__global__ __launch_bounds__(1024) void sort_kernel(
    const float* __restrict__ in, u32* __restrict__ so, u32* __restrict__ skey,
    float4* __restrict__ sb4, float* __restrict__ sar, u64* __restrict__ valid)
{
  const int g = blockIdx.x;
  const int b = g / NC, c = g % NC;
  const float* __restrict__ base = in + (size_t)b * NN * 11;
  __shared__ u64 sk[9216];
  const int tid = threadIdx.x;

  for (int p = tid; p < NN; p += 1024) {
    float sc = base[p * 11 + 7 + c];
    float s = (sc > 0.1f) ? sc : -INFINITY;
    sk[PHYS(p)] = ((u64)sort_key(s) << 16) | (u32)p;
  }
  __syncthreads();
  {
    const int pb = 9 * tid;
    u64 x[8];
#pragma unroll
    for (int a = 0; a < 8; ++a) x[a] = sk[pb + a];
    const bool u8 = ((tid & 1) == 0);
    CEX(0, 1, true); CEX(2, 3, false); CEX(4, 5, true); CEX(6, 7, false);
    CEX(0, 2, true); CEX(1, 3, true); CEX(4, 6, false); CEX(5, 7, false);
    CEX(0, 1, true); CEX(2, 3, true); CEX(4, 5, false); CEX(6, 7, false);
    CEX(0, 4, u8); CEX(1, 5, u8); CEX(2, 6, u8); CEX(3, 7, u8);
    CEX(0, 2, u8); CEX(1, 3, u8); CEX(4, 6, u8); CEX(5, 7, u8);
    CEX(0, 1, u8); CEX(2, 3, u8); CEX(4, 5, u8); CEX(6, 7, u8);
#pragma unroll
    for (int a = 0; a < 8; ++a) sk[pb + a] = x[a];
  }
  __syncthreads();
  for (int k = 16; k <= NN; k <<= 1) {
    for (int j = k >> 1; j >= 8; j >>= 1) {
      for (int t = tid; t < NN / 2; t += 1024) {
        int i = (t << 1) - (t & (j - 1));
        int q = i | j;
        int pi = PHYS(i), pq = PHYS(q);
        u64 ka = sk[pi], kb = sk[pq];
        bool up = ((i & k) == 0);
        if ((ka > kb) == up) { sk[pi] = kb; sk[pq] = ka; }
      }
      __syncthreads();
    }
    {
      const int bidx = tid << 3;
      const bool up = ((bidx & k) == 0);
      const int pb = 9 * tid;
      u64 x[8];
#pragma unroll
      for (int a = 0; a < 8; ++a) x[a] = sk[pb + a];
      CEX(0, 4, up); CEX(1, 5, up); CEX(2, 6, up); CEX(3, 7, up);
      CEX(0, 2, up); CEX(1, 3, up); CEX(4, 6, up); CEX(5, 7, up);
      CEX(0, 1, up); CEX(2, 3, up); CEX(4, 5, up); CEX(6, 7, up);
#pragma unroll
      for (int a = 0; a < 8; ++a) sk[pb + a] = x[a];
    }
    __syncthreads();
  }

  const int lane = tid & 63;
#pragma unroll
  for (int k = 0; k < 8; ++k) {
    int p = k * 1024 + tid;
    u64 kk = sk[PHYS(p)];
    int orig = (int)(kk & 0xFFFFu);
    u32 key32 = (u32)(kk >> 16);
    so[g * NN + p] = (u32)orig;
    skey[g * NN + p] = key32;
    const float* r = base + orig * 11;
    float x = r[0], y = r[1], l = r[3], wd = r[4];
    float hx = l * 0.5f, hy = wd * 0.5f;
    float x1 = x - hx, y1 = y - hy, x2 = x + hx, y2 = y + hy;
    sb4[g * NN + p] = make_float4(x1, y1, x2, y2);
    sar[g * NN + p] = (x2 - x1) * (y2 - y1);
    u64 bal = __ballot(key32 != 0xFF800000u);
    if (lane == 0) valid[g * 128 + (p >> 6)] = bal;
  }
}

// ================= prefix build: rows 0..2047 x words 0..31 (upper tri) ====
__global__ __launch_bounds__(PB_TPB) void build_prefix_kernel(
    const float4* __restrict__ sb4, const float* __restrict__ sar,
    u64* __restrict__ pmat)
{
  const int wib = __builtin_amdgcn_readfirstlane((int)(threadIdx.x >> 6));
  const int lane = threadIdx.x & 63;
  const int W = blockIdx.x * (PB_TPB / 64) + wib;
  if (W >= NG * PUNITS_PER_G) return;
  const int g = W / PUNITS_PER_G;
  int r = W - g * PUNITS_PER_G;
  int rb = 0, cum = 0;
  while (r >= cum + (PR_CH - rb)) { cum += PR_CH - rb; ++rb; }
  const int jw = rb + (r - cum);
  const double CMULT = 0.25 * (1.0 + 0x1p-24);   // exact in double

  const int col = jw * 64 + lane;
  const float4 J = sb4[(size_t)g * NN + col];
  const float jar = sar[(size_t)g * NN + col];
  const float4* __restrict__ Ib = sb4 + (size_t)g * NN + rb * 64;
  const float* __restrict__ Ia = sar + (size_t)g * NN + rb * 64;

  u32 accLo = 0, accHi = 0;
  for (int rr = 0; rr < 64; ++rr) {
    const float4 I = Ib[rr];            // uniform -> s_load
    const float iar = Ia[rr];
    const bool sel = (lane == rr);
    float iw = fminf(I.z, J.z) - fmaxf(I.x, J.x);
    float ih = fminf(I.w, J.w) - fmaxf(I.y, J.y);
    iw = fmaxf(iw, 0.0f); ih = fmaxf(ih, 0.0f);
    float inter = iw * ih;
    float denom = ((iar + jar) - inter) + 1e-8f;
    u64 cand = __ballot((double)inter > CMULT * (double)denom);
    accLo = sel ? (u32)(cand & 0xffffffffu) : accLo;
    accHi = sel ? (u32)(cand >> 32) : accHi;
  }
  pmat[((size_t)(g * PR_CH + jw)) * PR_ROWS + rb * 64 + lane] =
      ((u64)accHi << 32) | accLo;
}

// ======= prefix scan v2: SINGLE WAVE per class, barrier-free, lazy gather ==
// Arriving at chunk cc: suppressed(cc) = ~valid[cc] | OR over prior keepers'
// word-cc entries (gathered 64-wide from transposed pmat + shfl-OR-reduce).
// Serial resolve on the prefetched diag word; keepers append IN RANK ORDER
// to an LDS list -> kept_key/kept_pos written directly from it.
__global__ __launch_bounds__(64) void scan_prefix_kernel(
    const u64* __restrict__ pmat, const u64* __restrict__ valid,
    const u32* __restrict__ skey, u32* __restrict__ kept_key,
    u32* __restrict__ kept_pos, u32* __restrict__ kept_cnt,
    u32* __restrict__ flags)
{
  const int g = blockIdx.x;
  const int lane = threadIdx.x;
  __shared__ u16 klist[PR_ROWS];       // keeper rows, rank order (4 KB)
  const u64* __restrict__ pm = pmat + (size_t)g * PR_CH * PR_ROWS;

  int klen = 0;
  for (int cc = 0; cc < PR_CH; ++cc) {
    const u64* __restrict__ col = pm + (size_t)cc * PR_ROWS;
    // diag word for the resolve (issued early; completes under the gather)
    u64 diag = col[cc * 64 + lane];
    // lazy gather: OR word-cc entries of all prior keepers
    u64 acc = 0;
    for (int i = lane; i < klen; i += 64) acc |= col[klist[i]];
#pragma unroll
    for (int off = 32; off > 0; off >>= 1)
      acc |= (u64)__shfl_xor((long long)acc, off);
    u64 m = ~(acc | ~valid[g * 128 + cc]);   // alive candidates of chunk cc
    // serial in-wave resolve
    while (m) {
      int bp = __ffsll(m) - 1;
      if (lane == 0) klist[klen] = (u16)(cc * 64 + bp);
      ++klen;
      m &= ~(1ull << bp);
      u32 rlo = (u32)__builtin_amdgcn_readlane((int)(u32)(diag & 0xffffffffu), bp);
      u32 rhi = (u32)__builtin_amdgcn_readlane((int)(u32)(diag >> 32), bp);
      m &= ~(((u64)rhi << 32) | rlo);
    }
  }

  if (lane == 0) {
    flags[g] = (klen >= KEEP_CAP) ? 1u : 0u;
    if (klen >= KEEP_CAP) kept_cnt[g] = KEEP_CAP;
  }
  if (klen >= KEEP_CAP) {
#pragma unroll
    for (int it = 0; it < KEEP_CAP / 64; ++it) {
      int i = it * 64 + lane;
      int row = klist[i];
      kept_key[g * KEEP_CAP + i] = skey[g * NN + row];
      kept_pos[g * KEEP_CAP + i] = (u32)row;
    }
  }
}

// ================= full path (flag-gated fallback; r10 build) =============
#define UNITS_PER_G 1088
#define BUILD_TPB 256
#define BUILD_BLOCKS 1632

__global__ __launch_bounds__(BUILD_TPB) void build_kernel(
    const float4* __restrict__ sb4, const float* __restrict__ sar,
    u64* __restrict__ mat, const u32* __restrict__ flags, int g0, int P)
{
  const int wib = __builtin_amdgcn_readfirstlane((int)(threadIdx.x >> 6));
  const int lane = threadIdx.x & 63;
  const int W = blockIdx.x * (BUILD_TPB / 64) + wib;
  const int NUNITS = P * UNITS_PER_G;
  const double CMULT = 0.25 * (1.0 + 0x1p-24);

  for (int u = W; u < NUNITS; u += BUILD_BLOCKS * (BUILD_TPB / 64)) {
    const int gp = u / UNITS_PER_G;
    if (flags[g0 + gp]) continue;       // early path already solved this class
    int r = u - gp * UNITS_PER_G;
    int rb8 = 0, cum = 0;
    while (r >= cum + 8 * (16 - rb8)) { cum += 8 * (16 - rb8); ++rb8; }
    const int idx = r - cum;
    const int nb = 16 - rb8;
    const int rb = rb8 * 8 + idx / nb;
    const int jb = rb8 + idx % nb;

    const int g = g0 + gp;
    float jx1[8], jy1[8], jx2[8], jy2[8], jar[8];
#pragma unroll
    for (int wq = 0; wq < 8; ++wq) {
      const int col = jb * 512 + wq * 64 + lane;
      const float4 J = sb4[(size_t)g * NN + col];
      jx1[wq] = J.x; jy1[wq] = J.y; jx2[wq] = J.z; jy2[wq] = J.w;
      jar[wq] = sar[(size_t)g * NN + col];
    }
    u32 accLo[8], accHi[8];
#pragma unroll
    for (int wq = 0; wq < 8; ++wq) { accLo[wq] = 0u; accHi[wq] = 0u; }

    const float4* __restrict__ Ib = sb4 + (size_t)g * NN + rb * 64;
    const float* __restrict__ Ia = sar + (size_t)g * NN + rb * 64;

    for (int rr = 0; rr < 64; ++rr) {
      const float4 I = Ib[rr];
      const float iar = Ia[rr];
      const bool sel = (lane == rr);
#pragma unroll
      for (int wq = 0; wq < 8; ++wq) {
        float iw = fminf(I.z, jx2[wq]) - fmaxf(I.x, jx1[wq]);
        float ih = fminf(I.w, jy2[wq]) - fmaxf(I.y, jy1[wq]);
        iw = fmaxf(iw, 0.0f); ih = fmaxf(ih, 0.0f);
        float inter = iw * ih;
        float denom = ((iar + jar[wq]) - inter) + 1e-8f;
        u64 cand = __ballot((double)inter > CMULT * (double)denom);
        accLo[wq] = sel ? (u32)(cand & 0xffffffffu) : accLo[wq];
        accHi[wq] = sel ? (u32)(cand >> 32) : accHi[wq];
      }
    }
    u64* dst = mat + ((size_t)(gp * NN + rb * 64 + lane)) * 128 + jb * 8;
    uint4* d4 = (uint4*)dst;
    d4[0] = make_uint4(accLo[0], accHi[0], accLo[1], accHi[1]);
    d4[1] = make_uint4(accLo[2], accHi[2], accLo[3], accHi[3]);
    d4[2] = make_uint4(accLo[4], accHi[4], accLo[5], accHi[5]);
    d4[3] = make_uint4(accLo[6], accHi[6], accLo[7], accHi[7]);
  }
}

__global__ __launch_bounds__(1024) void scan_kernel(
    const u64* __restrict__ mat, const u64* __restrict__ valid,
    const u32* __restrict__ skey, u64* __restrict__ alive_out,
    u32* __restrict__ kept_key, u32* __restrict__ kept_pos,
    u32* __restrict__ kept_cnt, const u32* __restrict__ flags, int g0)
{
  const int gp = blockIdx.x, g = g0 + gp;
  if (flags[g]) return;
  const int tid = threadIdx.x;
  const int wv = tid >> 6, lane = tid & 63;
  const int wl = tid & 127, grp = tid >> 7;
  __shared__ u64 remv[128];
  __shared__ u64 keepw[128];
  __shared__ u64 keepS;
  __shared__ u32 prefixL[128];

  if (tid < 128) remv[tid] = ~valid[g * 128 + tid];
  __syncthreads();

  const u64* __restrict__ pm = mat + (size_t)gp * NN * 128;
  u64 rwDiag = 0, rwDiagNext = 0;
  if (wv == 0) rwDiag = pm[((size_t)lane) * 128 + 0];

  for (int cc = 0; cc < 128; ++cc) {
    const int w = cc + 1 + wl;
    const bool act = (w < 128);
    u64 rw[8];
    if (act) {
#pragma unroll
      for (int k = 0; k < 8; ++k)
        rw[k] = pm[((size_t)(cc * 64 + grp * 8 + k)) * 128 + w];
    }
    if (wv == 0) {
      u64 m = ~remv[cc];
      u64 keepm = 0;
      while (m) {
        int bp = __ffsll(m) - 1;
        keepm |= 1ull << bp;
        m &= ~(1ull << bp);
        u32 rlo = (u32)__builtin_amdgcn_readlane((int)(u32)(rwDiag & 0xffffffffu), bp);
        u32 rhi = (u32)__builtin_amdgcn_readlane((int)(u32)(rwDiag >> 32), bp);
        m &= ~(((u64)rhi << 32) | rlo);
      }
      if (lane == 0) { keepw[cc] = keepm; keepS = keepm; }
      if (cc + 1 < 128) rwDiagNext = pm[((size_t)((cc + 1) * 64 + lane)) * 128 + (cc + 1)];
    }
    __syncthreads();
    if (act) {
      const u32 kmg = (u32)((keepS >> (grp * 8)) & 0xffu);
      u64 acc = 0;
#pragma unroll
      for (int k = 0; k < 8; ++k)
        if ((kmg >> k) & 1u) acc |= rw[k];
      if (acc) atomicOr(&remv[w], acc);
    }
    if (wv == 0) rwDiag = rwDiagNext;
    __syncthreads();
  }

  if (tid == 0) {
    u32 acc = 0;
    for (int i = 0; i < 128; ++i) { prefixL[i] = acc; acc += (u32)__popcll(keepw[i]); }
    kept_cnt[g] = acc;
  }
  __syncthreads();
  if (tid < 128) alive_out[g * 128 + tid] = keepw[tid];
  for (int p = tid; p < NN; p += 1024) {
    int wd = p >> 6;
    u64 kw = keepw[wd];
    if ((kw >> (p & 63)) & 1ull) {
      u32 rank = prefixL[wd] + (u32)__popcll(kw & ((1ull << (p & 63)) - 1ull));
      if (rank < KEEP_CAP) {
        kept_key[g * KEEP_CAP + rank] = skey[g * NN + p];
        kept_pos[g * KEEP_CAP + rank] = (u32)p;
      }
    }
  }
}

// ================= old path (fallback when ws too small, r2) ==============
__global__ __launch_bounds__(1024) void nms_kernel(
    const float* __restrict__ in, u32* __restrict__ sorted_orig,
    u64* __restrict__ alive_out, u32* __restrict__ kept_key,
    u32* __restrict__ kept_pos, u32* __restrict__ kept_cnt)
{
  const int g = blockIdx.x;
  const int b = g / NC, c = g % NC;
  const float* __restrict__ base = in + (size_t)b * NN * 11;
  __shared__ u32 keys[NN];
  __shared__ uint16_t sidx[NN];
  __shared__ float4 keeperBuf[2][64];
  __shared__ int nkBuf[2];
  __shared__ u64 aliveArr[128];
  __shared__ u32 prefix[128];
  const int tid = threadIdx.x;
  const int w = tid >> 6, lane = tid & 63;

  for (int p = tid; p < NN; p += 1024) {
    float sc = base[p * 11 + 7 + c];
    float s = (sc > 0.1f) ? sc : -INFINITY;
    keys[p] = sort_key(s);
    sidx[p] = (uint16_t)p;
  }
  __syncthreads();
  for (int k = 2; k <= NN; k <<= 1) {
    for (int j = k >> 1; j > 0; j >>= 1) {
      for (int t = tid; t < NN / 2; t += 1024) {
        int i = (t << 1) - (t & (j - 1));
        int q = i | j;
        u32 ka = keys[i], kb = keys[q];
        uint16_t ia = sidx[i], ib = sidx[q];
        bool gt = (ka > kb) || (ka == kb && ia > ib);
        bool up = ((i & k) == 0);
        if (gt == up) { keys[i] = kb; keys[q] = ka; sidx[i] = ib; sidx[q] = ia; }
      }
      __syncthreads();
    }
  }
  float bx1[8], by1[8], bx2[8], by2[8], barea[8];
  u64 alive[8];
#pragma unroll
  for (int k = 0; k < 8; ++k) {
    int p = k * 1024 + tid;
    u32 key = keys[p];
    int orig = sidx[p];
    sorted_orig[g * NN + p] = (u32)orig;
    const float* r = base + orig * 11;
    float x = r[0], y = r[1], l = r[3], wd = r[4];
    float hx = l * 0.5f, hy = wd * 0.5f;
    bx1[k] = x - hx; by1[k] = y - hy; bx2[k] = x + hx; by2[k] = y + hy;
    barea[k] = (bx2[k] - bx1[k]) * (by2[k] - by1[k]);
    alive[k] = __ballot(key != 0xFF800000u);
  }
  for (int cc = 0; cc < 128; ++cc) {
    __syncthreads();
    int nk_prev = (cc > 0) ? nkBuf[(cc - 1) & 1] : 0;
    if (nk_prev > 0) {
      const int par = (cc - 1) & 1;
      for (int j = 0; j < nk_prev; ++j) {
        float4 K = keeperBuf[par][j];
        float ka = (K.z - K.x) * (K.w - K.y);
#pragma unroll
        for (int k = 0; k < 8; ++k) {
          if ((k * 16 + w) < cc) continue;
          if (alive[k] == 0ull) continue;
          float iw = fminf(bx2[k], K.z) - fmaxf(bx1[k], K.x);
          float ih = fminf(by2[k], K.w) - fmaxf(by1[k], K.y);
          iw = fmaxf(iw, 0.0f); ih = fmaxf(ih, 0.0f);
          float inter = iw * ih;
          float denom = (barea[k] + ka) - inter + 1e-8f;
          float t = 0.25f * denom;
          u64 sup = __ballot(inter > t);
          u64 wnd = __ballot(inter > t && inter <= t * NMS_EPS);
          if (wnd) {
            bool bb = inter > t;
            if (bb && inter <= t * NMS_EPS) bb = (inter / denom) > 0.25f;
            sup = __ballot(bb);
          }
          alive[k] &= ~sup;
        }
      }
    }
    if (w == (cc & 15)) {
      float mx1 = 0.f, my1 = 0.f, mx2 = 0.f, my2 = 0.f, ma = 0.f;
      u64 m = 0ull;
#pragma unroll
      for (int k = 0; k < 8; ++k) if (k == (cc >> 4)) {
        mx1 = bx1[k]; my1 = by1[k]; mx2 = bx2[k]; my2 = by2[k]; ma = barea[k];
        m = alive[k];
      }
      u64 keepm = 0ull;
      int nk = 0;
      while (m) {
        int bp = __ffsll(m) - 1;
        keepm |= 1ull << bp;
        m &= ~(1ull << bp);
        float kx1 = __shfl(mx1, bp), ky1 = __shfl(my1, bp);
        float kx2 = __shfl(mx2, bp), ky2 = __shfl(my2, bp);
        float ka = (kx2 - kx1) * (ky2 - ky1);
        float iw = fminf(mx2, kx2) - fmaxf(mx1, kx1);
        float ih = fminf(my2, ky2) - fmaxf(my1, ky1);
        iw = fmaxf(iw, 0.0f); ih = fmaxf(ih, 0.0f);
        float inter = iw * ih;
        float denom = (ma + ka) - inter + 1e-8f;
        float t = 0.25f * denom;
        u64 sup = __ballot(inter > t);
        u64 wnd = __ballot(inter > t && inter <= t * NMS_EPS);
        if (wnd) {
          bool bb = inter > t;
          if (bb && inter <= t * NMS_EPS) bb = (inter / denom) > 0.25f;
          sup = __ballot(bb);
        }
        m &= ~sup;
        if (lane == bp) keeperBuf[cc & 1][nk] = make_float4(mx1, my1, mx2, my2);
        nk++;
      }
#pragma unroll
      for (int k = 0; k < 8; ++k) if (k == (cc >> 4)) alive[k] = keepm;
      if (lane == 0) nkBuf[cc & 1] = nk;
    }
  }
  __syncthreads();
  if (lane == 0) {
#pragma unroll
    for (int k = 0; k < 8; ++k) aliveArr[k * 16 + w] = alive[k];
  }
  __syncthreads();
  if (tid == 0) {
    u32 acc = 0;
    for (int i = 0; i < 128; ++i) { prefix[i] = acc; acc += (u32)__popcll(aliveArr[i]); }
    kept_cnt[g] = acc;
  }
  __syncthreads();
  for (int i = tid; i < 128; i += 1024) alive_out[g * 128 + i] = aliveArr[i];
#pragma unroll
  for (int k = 0; k < 8; ++k) {
    int word = k * 16 + w;
    u64 a = alive[k];
    if ((a >> lane) & 1ull) {
      u32 rank = prefix[word] + (u32)__popcll(a & ((1ull << lane) - 1ull));
      if (rank < KEEP_CAP) {
        int p = k * 1024 + tid;
        kept_key[g * KEEP_CAP + rank] = keys[p];
        kept_pos[g * KEEP_CAP + rank] = (u32)p;
      }
    }
  }
}

// ================= shared top-k / output =================
__global__ __launch_bounds__(512) void topk_kernel(
    const float* __restrict__ in, const u32* __restrict__ sorted_orig,
    const u64* __restrict__ alive_ws, const u32* __restrict__ kept_key,
    const u32* __restrict__ kept_pos, const u32* __restrict__ kept_cnt,
    float* __restrict__ out)
{
  const int b = blockIdx.x;
  const int tid = threadIdx.x;
  __shared__ u64 sk[2048];
  __shared__ int sT[3];
  if (tid < 3) sT[tid] = (int)kept_cnt[b * 3 + tid];
  __syncthreads();
  const int K0 = sT[0], K1 = sT[1], K2 = sT[2];
  const int Ttot = K0 + K1 + K2;

  for (int s = tid; s < 2048; s += 512) {
    u64 key = ~0ull;
    int c = s >> 9;
    if (c < NC) {
      int r = s & 511;
      int Kc = (c == 0) ? K0 : (c == 1) ? K1 : K2;
      if (r < min(Kc, KEEP_CAP)) {
        int g = b * 3 + c;
        u64 k32 = kept_key[g * KEEP_CAP + r];
        u32 pos = kept_pos[g * KEEP_CAP + r];
        key = (k32 << 15) | (u32)(c * NN + pos);
      }
    }
    sk[s] = key;
  }
  __syncthreads();
  for (int k = 2; k <= 2048; k <<= 1) {
    for (int j = k >> 1; j > 0; j >>= 1) {
      for (int t = tid; t < 1024; t += 512) {
        int i = (t << 1) - (t & (j - 1));
        int q = i | j;
        u64 ka = sk[i], kb = sk[q];
        bool up = ((i & k) == 0);
        if ((ka > kb) == up) { sk[i] = kb; sk[q] = ka; }
      }
      __syncthreads();
    }
  }
  const int navail = min(K0, KEEP_CAP) + min(K1, KEEP_CAP) + min(K2, KEEP_CAP);
  for (int r = tid; r < MAXN; r += 512) {
    int c, pos; float sval;
    if (r < navail) {
      u64 key = sk[r];
      u32 flat = (u32)(key & 32767u);
      c = (int)(flat >> 13); pos = (int)(flat & 8191);
      u32 k32 = (u32)(key >> 15);
      u32 o = ~k32;
      u32 bits = (o & 0x80000000u) ? (o ^ 0x80000000u) : ~o;
      sval = __uint_as_float(bits);
    } else {
      int need = r - Ttot;
      int fflat = 0;
      for (int wd = 0; wd < 384; ++wd) {
        u64 a = alive_ws[b * 384 + wd];
        int z = 64 - __popcll(a);
        if (need < z) {
          u64 na = ~a;
          for (int it = 0; it < need; ++it) na &= na - 1ull;
          fflat = wd * 64 + (__ffsll(na) - 1);
          break;
        }
        need -= z;
      }
      c = fflat >> 13; pos = fflat & 8191;
      sval = -INFINITY;
    }
    u32 orig = sorted_orig[(b * 3 + c) * NN + pos];
    const float* row = in + ((size_t)b * NN + orig) * 11;
    const float PI_F = 3.14159265358979323846f;
    float theta = row[6];
    float v = theta / PI_F;
    float fl = floorf(v + 1.0f);
    float lp = theta - fl * PI_F;
    float ang = lp + (1.0f - row[10]) * PI_F;
    float* ob = out + ((size_t)b * MAXN + r) * 7;
    ob[0] = row[0]; ob[1] = row[1]; ob[2] = row[2];
    ob[3] = row[3]; ob[4] = row[4]; ob[5] = row[5]; ob[6] = ang;
    out[NB * MAXN * 7 + b * MAXN + r] = (float)c;
    out[NB * MAXN * 7 + NB * MAXN + b * MAXN + r] = sval;
  }
}

extern "C" void kernel_launch(void* const* d_in, const int* in_sizes, int n_in,
                              void* d_out, int out_size, void* d_ws, size_t ws_size,
                              hipStream_t stream) {
  const float* in = (const float*)d_in[0];
  float* out = (float*)d_out;
  char* ws = (char*)d_ws;

  int P = 0;
  const int cands[6] = {12, 6, 4, 3, 2, 1};
  for (int ci = 0; ci < 6; ++ci) {
    if ((size_t)NMAT + (size_t)cands[ci] * MATB <= ws_size) { P = cands[ci]; break; }
  }

  if (P > 0) {
    u32* so = (u32*)(ws + NSO);
    u32* skey = (u32*)(ws + NSKEY);
    float4* sb4 = (float4*)(ws + NSB4);
    float* sar = (float*)(ws + NSAR);
    u64* valid = (u64*)(ws + NVAL);
    u64* alive = (u64*)(ws + NALV);
    u32* kkey = (u32*)(ws + NKKEY);
    u32* kpos = (u32*)(ws + NKPOS);
    u32* kcnt = (u32*)(ws + NKCNT);
    u32* flags = (u32*)(ws + NFLG);
    u64* pmat = (u64*)(ws + PMAT);
    u64* mat = (u64*)(ws + NMAT);

    sort_kernel<<<dim3(NG), dim3(1024), 0, stream>>>(
        in, so, skey, sb4, sar, valid);
    build_prefix_kernel<<<dim3(PB_BLOCKS), dim3(PB_TPB), 0, stream>>>(
        sb4, sar, pmat);
    scan_prefix_kernel<<<dim3(NG), dim3(64), 0, stream>>>(
        pmat, valid, skey, kkey, kpos, kcnt, flags);
    for (int g0 = 0; g0 < NG; g0 += P) {
      build_kernel<<<dim3(BUILD_BLOCKS), dim3(BUILD_TPB), 0, stream>>>(
          sb4, sar, mat, flags, g0, P);
      scan_kernel<<<dim3(P), dim3(1024), 0, stream>>>(
          mat, valid, skey, alive, kkey, kpos, kcnt, flags, g0);
    }
    topk_kernel<<<dim3(NB), dim3(512), 0, stream>>>(
        in, so, alive, kkey, kpos, kcnt, out);
  } else {
    u32* sorted_orig = (u32*)(ws + WS_SORTED_ORIG);
    u64* alive = (u64*)(ws + WS_ALIVE);
    u32* kept_key = (u32*)(ws + WS_KEPT_KEY);
    u32* kept_pos = (u32*)(ws + WS_KEPT_POS);
    u32* kept_cnt = (u32*)(ws + WS_KEPT_CNT);
    nms_kernel<<<dim3(NG), dim3(1024), 0, stream>>>(
        in, sorted_orig, alive, kept_key, kept_pos, kept_cnt);
    topk_kernel<<<dim3(NB), dim3(512), 0, stream>>>(
        in, sorted_orig, alive, kept_key, kept_pos, kept_cnt, out);
  }
}

// Round 15
// 141.905 us; speedup vs baseline: 2.1069x; 2.1069x over previous
//
#include <hip/hip_runtime.h>
#include <stdint.h>

#pragma clang fp contract(off)

#define NB 4
#define NN 8192
#define NC 3
#define NG 12
#define MAXN 500
#define KEEP_CAP 512

typedef unsigned long long u64;
typedef uint32_t u32;
typedef uint16_t u16;

// ---------- ws layout (bytes) ----------
#define NSO   0u          // u32 [12][8192] sorted->orig
#define NSKEY 393216u     // u32 [12][8192] sorted key32
#define NSB4  786432u     // float4 [12][8192]
#define NSAR  2359296u    // f32 [12][8192]
#define NVAL  2752512u    // u64 [12][128] valid bits
#define NALV  2764800u    // u64 [12][128] keep bits
#define NKKEY 2777088u    // u32 [12][512]
#define NKPOS 2801664u    // u32 [12][512]
#define NKCNT 2826240u    // u32 [12]
#define NFLG  2826304u    // u32 [12] early-path flags
#define PMAT  3145728u    // u64 [12][32][2048] prefix matrix (6 MB), TRANSPOSED
#define NMAT  9437184u    // full matrices start
#define MATB  8388608ull  // 8192*128*8 per problem

// prefix-NMS parameters
#define PR_CH   32        // 32 chunks of 64 = 2048 rows
#define PR_ROWS 2048
#define PUNITS_PER_G 528  // sum_{rb=0}^{31}(32-rb)
#define PB_TPB 256
#define PB_BLOCKS 1584    // 6336 waves = 12*528 units, 1/wave

// ---------- old-path (fallback) ws layout ----------
#define WS_SORTED_ORIG 0
#define WS_ALIVE       393216
#define WS_KEPT_KEY    405504
#define WS_KEPT_POS    430080
#define WS_KEPT_CNT    454656
#define NMS_EPS 1.0000004f

__device__ __forceinline__ u32 sort_key(float s) {
  u32 b = __float_as_uint(s);
  u32 o = (b & 0x80000000u) ? ~b : (b | 0x80000000u);
  return ~o;   // ascending key == descending float; -inf -> 0xFF800000
}

// ================= sort (unchanged r6) =================
#define PHYS(i) ((i) + ((i) >> 3))
#define CEX(A, B, UP) \
  { if ((x[A] > x[B]) == (UP)) { u64 tt = x[A]; x[A] = x[B]; x[B] = tt; } }

__global__ __launch_bounds__(1024) void sort_kernel(
    const float* __restrict__ in, u32* __restrict__ so, u32* __restrict__ skey,
    float4* __restrict__ sb4, float* __restrict__ sar, u64* __restrict__ valid)
{
  const int g = blockIdx.x;
  const int b = g / NC, c = g % NC;
  const float* __restrict__ base = in + (size_t)b * NN * 11;
  __shared__ u64 sk[9216];
  const int tid = threadIdx.x;

  for (int p = tid; p < NN; p += 1024) {
    float sc = base[p * 11 + 7 + c];
    float s = (sc > 0.1f) ? sc : -INFINITY;
    sk[PHYS(p)] = ((u64)sort_key(s) << 16) | (u32)p;
  }
  __syncthreads();
  {
    const int pb = 9 * tid;
    u64 x[8];
#pragma unroll
    for (int a = 0; a < 8; ++a) x[a] = sk[pb + a];
    const bool u8 = ((tid & 1) == 0);
    CEX(0, 1, true); CEX(2, 3, false); CEX(4, 5, true); CEX(6, 7, false);
    CEX(0, 2, true); CEX(1, 3, true); CEX(4, 6, false); CEX(5, 7, false);
    CEX(0, 1, true); CEX(2, 3, true); CEX(4, 5, false); CEX(6, 7, false);
    CEX(0, 4, u8); CEX(1, 5, u8); CEX(2, 6, u8); CEX(3, 7, u8);
    CEX(0, 2, u8); CEX(1, 3, u8); CEX(4, 6, u8); CEX(5, 7, u8);
    CEX(0, 1, u8); CEX(2, 3, u8); CEX(4, 5, u8); CEX(6, 7, u8);
#pragma unroll
    for (int a = 0; a < 8; ++a) sk[pb + a] = x[a];
  }
  __syncthreads();
  for (int k = 16; k <= NN; k <<= 1) {
    for (int j = k >> 1; j >= 8; j >>= 1) {
      for (int t = tid; t < NN / 2; t += 1024) {
        int i = (t << 1) - (t & (j - 1));
        int q = i | j;
        int pi = PHYS(i), pq = PHYS(q);
        u64 ka = sk[pi], kb = sk[pq];
        bool up = ((i & k) == 0);
        if ((ka > kb) == up) { sk[pi] = kb; sk[pq] = ka; }
      }
      __syncthreads();
    }
    {
      const int bidx = tid << 3;
      const bool up = ((bidx & k) == 0);
      const int pb = 9 * tid;
      u64 x[8];
#pragma unroll
      for (int a = 0; a < 8; ++a) x[a] = sk[pb + a];
      CEX(0, 4, up); CEX(1, 5, up); CEX(2, 6, up); CEX(3, 7, up);
      CEX(0, 2, up); CEX(1, 3, up); CEX(4, 6, up); CEX(5, 7, up);
      CEX(0, 1, up); CEX(2, 3, up); CEX(4, 5, up); CEX(6, 7, up);
#pragma unroll
      for (int a = 0; a < 8; ++a) sk[pb + a] = x[a];
    }
    __syncthreads();
  }

  const int lane = tid & 63;
#pragma unroll
  for (int k = 0; k < 8; ++k) {
    int p = k * 1024 + tid;
    u64 kk = sk[PHYS(p)];
    int orig = (int)(kk & 0xFFFFu);
    u32 key32 = (u32)(kk >> 16);
    so[g * NN + p] = (u32)orig;
    skey[g * NN + p] = key32;
    const float* r = base + orig * 11;
    float x = r[0], y = r[1], l = r[3], wd = r[4];
    float hx = l * 0.5f, hy = wd * 0.5f;
    float x1 = x - hx, y1 = y - hy, x2 = x + hx, y2 = y + hy;
    sb4[g * NN + p] = make_float4(x1, y1, x2, y2);
    sar[g * NN + p] = (x2 - x1) * (y2 - y1);
    u64 bal = __ballot(key32 != 0xFF800000u);
    if (lane == 0) valid[g * 128 + (p >> 6)] = bal;
  }
}

// ================= prefix build: rows 0..2047 x words 0..31 (upper tri) ====
__global__ __launch_bounds__(PB_TPB) void build_prefix_kernel(
    const float4* __restrict__ sb4, const float* __restrict__ sar,
    u64* __restrict__ pmat)
{
  const int wib = __builtin_amdgcn_readfirstlane((int)(threadIdx.x >> 6));
  const int lane = threadIdx.x & 63;
  const int W = blockIdx.x * (PB_TPB / 64) + wib;
  if (W >= NG * PUNITS_PER_G) return;
  const int g = W / PUNITS_PER_G;
  int r = W - g * PUNITS_PER_G;
  int rb = 0, cum = 0;
  while (r >= cum + (PR_CH - rb)) { cum += PR_CH - rb; ++rb; }
  const int jw = rb + (r - cum);
  const double CMULT = 0.25 * (1.0 + 0x1p-24);   // exact in double

  const int col = jw * 64 + lane;
  const float4 J = sb4[(size_t)g * NN + col];
  const float jar = sar[(size_t)g * NN + col];
  const float4* __restrict__ Ib = sb4 + (size_t)g * NN + rb * 64;
  const float* __restrict__ Ia = sar + (size_t)g * NN + rb * 64;

  u32 accLo = 0, accHi = 0;
  for (int rr = 0; rr < 64; ++rr) {
    const float4 I = Ib[rr];            // uniform -> s_load
    const float iar = Ia[rr];
    const bool sel = (lane == rr);
    float iw = fminf(I.z, J.z) - fmaxf(I.x, J.x);
    float ih = fminf(I.w, J.w) - fmaxf(I.y, J.y);
    iw = fmaxf(iw, 0.0f); ih = fmaxf(ih, 0.0f);
    float inter = iw * ih;
    float denom = ((iar + jar) - inter) + 1e-8f;
    u64 cand = __ballot((double)inter > CMULT * (double)denom);
    accLo = sel ? (u32)(cand & 0xffffffffu) : accLo;
    accHi = sel ? (u32)(cand >> 32) : accHi;
  }
  pmat[((size_t)(g * PR_CH + jw)) * PR_ROWS + rb * 64 + lane] =
      ((u64)accHi << 32) | accLo;
}

// ======= prefix scan (r12 structure + fixpoint resolve + early exit) =======
// lane j of wave0 holds D_j = suppression word of chunk-row j. Greedy within
// the chunk via Jacobi fixpoint: K <- alive0 & ~OR_{j in K}(D_j & mask_{>j});
// after t iters rows 0..t-1 are final => exact greedy in <=64 iters (typ 3-6).
__global__ __launch_bounds__(1024) void scan_prefix_kernel(
    const u64* __restrict__ pmat, const u64* __restrict__ valid,
    const u32* __restrict__ skey, u32* __restrict__ kept_key,
    u32* __restrict__ kept_pos, u32* __restrict__ kept_cnt,
    u32* __restrict__ flags)
{
  const int g = blockIdx.x;
  const int tid = threadIdx.x;
  const int wv = tid >> 6, lane = tid & 63;
  const int wl = tid & 127, grp = tid >> 7;
  __shared__ u64 remv[PR_CH];
  __shared__ u64 keepw[PR_CH];
  __shared__ u64 keepS;
  __shared__ u32 prefixL[PR_CH];
  __shared__ u32 cntS;
  __shared__ int stopS;

  if (tid < PR_CH) { remv[tid] = ~valid[g * 128 + tid]; keepw[tid] = 0; }
  if (tid == 0) { cntS = 0; stopS = 0; }
  __syncthreads();

  const u64* __restrict__ pm = pmat + (size_t)g * PR_CH * PR_ROWS;
  u64 rwDiag = 0, rwDiagNext = 0;
  if (wv == 0) rwDiag = pm[lane];       // word 0, rows 0..63
  const u64 maskgt = (lane == 63) ? 0ull : (~0ull << (lane + 1));

  for (int cc = 0; cc < PR_CH; ++cc) {
    const int w = cc + 1 + wl;
    const bool act = (w < PR_CH);
    u64 rw[8];
    if (act) {
#pragma unroll
      for (int k = 0; k < 8; ++k)
        rw[k] = pm[(size_t)w * PR_ROWS + cc * 64 + grp * 8 + k];
    }
    if (wv == 0) {
      const u64 alive0 = ~remv[cc];
      u64 K = alive0;
      for (int it = 0; it < 64; ++it) {
        u64 contrib = ((K >> lane) & 1ull) ? (rwDiag & maskgt) : 0ull;
#pragma unroll
        for (int off = 32; off > 0; off >>= 1)
          contrib |= (u64)__shfl_xor((long long)contrib, off);
        u64 Knew = alive0 & ~contrib;
        if (Knew == K) break;
        K = Knew;
      }
      if (lane == 0) {
        keepw[cc] = K; keepS = K;
        cntS += (u32)__popcll(K);
        if (cntS >= KEEP_CAP) stopS = 1;
      }
      if (cc + 1 < PR_CH)
        rwDiagNext = pm[(size_t)(cc + 1) * PR_ROWS + (cc + 1) * 64 + lane];
    }
    __syncthreads();
    if (stopS) break;                    // uniform (read after barrier)
    if (act) {
      const u32 kmg = (u32)((keepS >> (grp * 8)) & 0xffu);
      u64 acc = 0;
#pragma unroll
      for (int k = 0; k < 8; ++k)
        if ((kmg >> k) & 1u) acc |= rw[k];
      if (acc) atomicOr(&remv[w], acc);
    }
    if (wv == 0) rwDiag = rwDiagNext;
    __syncthreads();
  }
  __syncthreads();

  if (tid == 0) {
    u32 acc = 0;
    for (int i = 0; i < PR_CH; ++i) { prefixL[i] = acc; acc += (u32)__popcll(keepw[i]); }
    cntS = acc;
    u32 ok = (acc >= KEEP_CAP) ? 1u : 0u;
    flags[g] = ok;
    if (ok) kept_cnt[g] = KEEP_CAP;
  }
  __syncthreads();
  if (cntS < KEEP_CAP) return;          // full path will handle this class
  for (int p = tid; p < PR_ROWS; p += 1024) {
    int wd = p >> 6;
    u64 kw = keepw[wd];
    if ((kw >> (p & 63)) & 1ull) {
      u32 rank = prefixL[wd] + (u32)__popcll(kw & ((1ull << (p & 63)) - 1ull));
      if (rank < KEEP_CAP) {
        kept_key[g * KEEP_CAP + rank] = skey[g * NN + p];
        kept_pos[g * KEEP_CAP + rank] = (u32)p;
      }
    }
  }
}

// ================= full path (flag-gated fallback; r10 build) =============
#define UNITS_PER_G 1088
#define BUILD_TPB 256
#define BUILD_BLOCKS 1632

__global__ __launch_bounds__(BUILD_TPB) void build_kernel(
    const float4* __restrict__ sb4, const float* __restrict__ sar,
    u64* __restrict__ mat, const u32* __restrict__ flags, int g0, int P)
{
  const int wib = __builtin_amdgcn_readfirstlane((int)(threadIdx.x >> 6));
  const int lane = threadIdx.x & 63;
  const int W = blockIdx.x * (BUILD_TPB / 64) + wib;
  const int NUNITS = P * UNITS_PER_G;
  const double CMULT = 0.25 * (1.0 + 0x1p-24);

  for (int u = W; u < NUNITS; u += BUILD_BLOCKS * (BUILD_TPB / 64)) {
    const int gp = u / UNITS_PER_G;
    if (flags[g0 + gp]) continue;       // early path already solved this class
    int r = u - gp * UNITS_PER_G;
    int rb8 = 0, cum = 0;
    while (r >= cum + 8 * (16 - rb8)) { cum += 8 * (16 - rb8); ++rb8; }
    const int idx = r - cum;
    const int nb = 16 - rb8;
    const int rb = rb8 * 8 + idx / nb;
    const int jb = rb8 + idx % nb;

    const int g = g0 + gp;
    float jx1[8], jy1[8], jx2[8], jy2[8], jar[8];
#pragma unroll
    for (int wq = 0; wq < 8; ++wq) {
      const int col = jb * 512 + wq * 64 + lane;
      const float4 J = sb4[(size_t)g * NN + col];
      jx1[wq] = J.x; jy1[wq] = J.y; jx2[wq] = J.z; jy2[wq] = J.w;
      jar[wq] = sar[(size_t)g * NN + col];
    }
    u32 accLo[8], accHi[8];
#pragma unroll
    for (int wq = 0; wq < 8; ++wq) { accLo[wq] = 0u; accHi[wq] = 0u; }

    const float4* __restrict__ Ib = sb4 + (size_t)g * NN + rb * 64;
    const float* __restrict__ Ia = sar + (size_t)g * NN + rb * 64;

    for (int rr = 0; rr < 64; ++rr) {
      const float4 I = Ib[rr];
      const float iar = Ia[rr];
      const bool sel = (lane == rr);
#pragma unroll
      for (int wq = 0; wq < 8; ++wq) {
        float iw = fminf(I.z, jx2[wq]) - fmaxf(I.x, jx1[wq]);
        float ih = fminf(I.w, jy2[wq]) - fmaxf(I.y, jy1[wq]);
        iw = fmaxf(iw, 0.0f); ih = fmaxf(ih, 0.0f);
        float inter = iw * ih;
        float denom = ((iar + jar[wq]) - inter) + 1e-8f;
        u64 cand = __ballot((double)inter > CMULT * (double)denom);
        accLo[wq] = sel ? (u32)(cand & 0xffffffffu) : accLo[wq];
        accHi[wq] = sel ? (u32)(cand >> 32) : accHi[wq];
      }
    }
    u64* dst = mat + ((size_t)(gp * NN + rb * 64 + lane)) * 128 + jb * 8;
    uint4* d4 = (uint4*)dst;
    d4[0] = make_uint4(accLo[0], accHi[0], accLo[1], accHi[1]);
    d4[1] = make_uint4(accLo[2], accHi[2], accLo[3], accHi[3]);
    d4[2] = make_uint4(accLo[4], accHi[4], accLo[5], accHi[5]);
    d4[3] = make_uint4(accLo[6], accHi[6], accLo[7], accHi[7]);
  }
}

__global__ __launch_bounds__(1024) void scan_kernel(
    const u64* __restrict__ mat, const u64* __restrict__ valid,
    const u32* __restrict__ skey, u64* __restrict__ alive_out,
    u32* __restrict__ kept_key, u32* __restrict__ kept_pos,
    u32* __restrict__ kept_cnt, const u32* __restrict__ flags, int g0)
{
  const int gp = blockIdx.x, g = g0 + gp;
  if (flags[g]) return;
  const int tid = threadIdx.x;
  const int wv = tid >> 6, lane = tid & 63;
  const int wl = tid & 127, grp = tid >> 7;
  __shared__ u64 remv[128];
  __shared__ u64 keepw[128];
  __shared__ u64 keepS;
  __shared__ u32 prefixL[128];

  if (tid < 128) remv[tid] = ~valid[g * 128 + tid];
  __syncthreads();

  const u64* __restrict__ pm = mat + (size_t)gp * NN * 128;
  u64 rwDiag = 0, rwDiagNext = 0;
  if (wv == 0) rwDiag = pm[((size_t)lane) * 128 + 0];

  for (int cc = 0; cc < 128; ++cc) {
    const int w = cc + 1 + wl;
    const bool act = (w < 128);
    u64 rw[8];
    if (act) {
#pragma unroll
      for (int k = 0; k < 8; ++k)
        rw[k] = pm[((size_t)(cc * 64 + grp * 8 + k)) * 128 + w];
    }
    if (wv == 0) {
      u64 m = ~remv[cc];
      u64 keepm = 0;
      while (m) {
        int bp = __ffsll(m) - 1;
        keepm |= 1ull << bp;
        m &= ~(1ull << bp);
        u32 rlo = (u32)__builtin_amdgcn_readlane((int)(u32)(rwDiag & 0xffffffffu), bp);
        u32 rhi = (u32)__builtin_amdgcn_readlane((int)(u32)(rwDiag >> 32), bp);
        m &= ~(((u64)rhi << 32) | rlo);
      }
      if (lane == 0) { keepw[cc] = keepm; keepS = keepm; }
      if (cc + 1 < 128) rwDiagNext = pm[((size_t)((cc + 1) * 64 + lane)) * 128 + (cc + 1)];
    }
    __syncthreads();
    if (act) {
      const u32 kmg = (u32)((keepS >> (grp * 8)) & 0xffu);
      u64 acc = 0;
#pragma unroll
      for (int k = 0; k < 8; ++k)
        if ((kmg >> k) & 1u) acc |= rw[k];
      if (acc) atomicOr(&remv[w], acc);
    }
    if (wv == 0) rwDiag = rwDiagNext;
    __syncthreads();
  }

  if (tid == 0) {
    u32 acc = 0;
    for (int i = 0; i < 128; ++i) { prefixL[i] = acc; acc += (u32)__popcll(keepw[i]); }
    kept_cnt[g] = acc;
  }
  __syncthreads();
  if (tid < 128) alive_out[g * 128 + tid] = keepw[tid];
  for (int p = tid; p < NN; p += 1024) {
    int wd = p >> 6;
    u64 kw = keepw[wd];
    if ((kw >> (p & 63)) & 1ull) {
      u32 rank = prefixL[wd] + (u32)__popcll(kw & ((1ull << (p & 63)) - 1ull));
      if (rank < KEEP_CAP) {
        kept_key[g * KEEP_CAP + rank] = skey[g * NN + p];
        kept_pos[g * KEEP_CAP + rank] = (u32)p;
      }
    }
  }
}

// ================= old path (fallback when ws too small, r2) ==============
__global__ __launch_bounds__(1024) void nms_kernel(
    const float* __restrict__ in, u32* __restrict__ sorted_orig,
    u64* __restrict__ alive_out, u32* __restrict__ kept_key,
    u32* __restrict__ kept_pos, u32* __restrict__ kept_cnt)
{
  const int g = blockIdx.x;
  const int b = g / NC, c = g % NC;
  const float* __restrict__ base = in + (size_t)b * NN * 11;
  __shared__ u32 keys[NN];
  __shared__ uint16_t sidx[NN];
  __shared__ float4 keeperBuf[2][64];
  __shared__ int nkBuf[2];
  __shared__ u64 aliveArr[128];
  __shared__ u32 prefix[128];
  const int tid = threadIdx.x;
  const int w = tid >> 6, lane = tid & 63;

  for (int p = tid; p < NN; p += 1024) {
    float sc = base[p * 11 + 7 + c];
    float s = (sc > 0.1f) ? sc : -INFINITY;
    keys[p] = sort_key(s);
    sidx[p] = (uint16_t)p;
  }
  __syncthreads();
  for (int k = 2; k <= NN; k <<= 1) {
    for (int j = k >> 1; j > 0; j >>= 1) {
      for (int t = tid; t < NN / 2; t += 1024) {
        int i = (t << 1) - (t & (j - 1));
        int q = i | j;
        u32 ka = keys[i], kb = keys[q];
        uint16_t ia = sidx[i], ib = sidx[q];
        bool gt = (ka > kb) || (ka == kb && ia > ib);
        bool up = ((i & k) == 0);
        if (gt == up) { keys[i] = kb; keys[q] = ka; sidx[i] = ib; sidx[q] = ia; }
      }
      __syncthreads();
    }
  }
  float bx1[8], by1[8], bx2[8], by2[8], barea[8];
  u64 alive[8];
#pragma unroll
  for (int k = 0; k < 8; ++k) {
    int p = k * 1024 + tid;
    u32 key = keys[p];
    int orig = sidx[p];
    sorted_orig[g * NN + p] = (u32)orig;
    const float* r = base + orig * 11;
    float x = r[0], y = r[1], l = r[3], wd = r[4];
    float hx = l * 0.5f, hy = wd * 0.5f;
    bx1[k] = x - hx; by1[k] = y - hy; bx2[k] = x + hx; by2[k] = y + hy;
    barea[k] = (bx2[k] - bx1[k]) * (by2[k] - by1[k]);
    alive[k] = __ballot(key != 0xFF800000u);
  }
  for (int cc = 0; cc < 128; ++cc) {
    __syncthreads();
    int nk_prev = (cc > 0) ? nkBuf[(cc - 1) & 1] : 0;
    if (nk_prev > 0) {
      const int par = (cc - 1) & 1;
      for (int j = 0; j < nk_prev; ++j) {
        float4 K = keeperBuf[par][j];
        float ka = (K.z - K.x) * (K.w - K.y);
#pragma unroll
        for (int k = 0; k < 8; ++k) {
          if ((k * 16 + w) < cc) continue;
          if (alive[k] == 0ull) continue;
          float iw = fminf(bx2[k], K.z) - fmaxf(bx1[k], K.x);
          float ih = fminf(by2[k], K.w) - fmaxf(by1[k], K.y);
          iw = fmaxf(iw, 0.0f); ih = fmaxf(ih, 0.0f);
          float inter = iw * ih;
          float denom = (barea[k] + ka) - inter + 1e-8f;
          float t = 0.25f * denom;
          u64 sup = __ballot(inter > t);
          u64 wnd = __ballot(inter > t && inter <= t * NMS_EPS);
          if (wnd) {
            bool bb = inter > t;
            if (bb && inter <= t * NMS_EPS) bb = (inter / denom) > 0.25f;
            sup = __ballot(bb);
          }
          alive[k] &= ~sup;
        }
      }
    }
    if (w == (cc & 15)) {
      float mx1 = 0.f, my1 = 0.f, mx2 = 0.f, my2 = 0.f, ma = 0.f;
      u64 m = 0ull;
#pragma unroll
      for (int k = 0; k < 8; ++k) if (k == (cc >> 4)) {
        mx1 = bx1[k]; my1 = by1[k]; mx2 = bx2[k]; my2 = by2[k]; ma = barea[k];
        m = alive[k];
      }
      u64 keepm = 0ull;
      int nk = 0;
      while (m) {
        int bp = __ffsll(m) - 1;
        keepm |= 1ull << bp;
        m &= ~(1ull << bp);
        float kx1 = __shfl(mx1, bp), ky1 = __shfl(my1, bp);
        float kx2 = __shfl(mx2, bp), ky2 = __shfl(my2, bp);
        float ka = (kx2 - kx1) * (ky2 - ky1);
        float iw = fminf(mx2, kx2) - fmaxf(mx1, kx1);
        float ih = fminf(my2, ky2) - fmaxf(my1, ky1);
        iw = fmaxf(iw, 0.0f); ih = fmaxf(ih, 0.0f);
        float inter = iw * ih;
        float denom = (ma + ka) - inter + 1e-8f;
        float t = 0.25f * denom;
        u64 sup = __ballot(inter > t);
        u64 wnd = __ballot(inter > t && inter <= t * NMS_EPS);
        if (wnd) {
          bool bb = inter > t;
          if (bb && inter <= t * NMS_EPS) bb = (inter / denom) > 0.25f;
          sup = __ballot(bb);
        }
        m &= ~sup;
        if (lane == bp) keeperBuf[cc & 1][nk] = make_float4(mx1, my1, mx2, my2);
        nk++;
      }
#pragma unroll
      for (int k = 0; k < 8; ++k) if (k == (cc >> 4)) alive[k] = keepm;
      if (lane == 0) nkBuf[cc & 1] = nk;
    }
  }
  __syncthreads();
  if (lane == 0) {
#pragma unroll
    for (int k = 0; k < 8; ++k) aliveArr[k * 16 + w] = alive[k];
  }
  __syncthreads();
  if (tid == 0) {
    u32 acc = 0;
    for (int i = 0; i < 128; ++i) { prefix[i] = acc; acc += (u32)__popcll(aliveArr[i]); }
    kept_cnt[g] = acc;
  }
  __syncthreads();
  for (int i = tid; i < 128; i += 1024) alive_out[g * 128 + i] = aliveArr[i];
#pragma unroll
  for (int k = 0; k < 8; ++k) {
    int word = k * 16 + w;
    u64 a = alive[k];
    if ((a >> lane) & 1ull) {
      u32 rank = prefix[word] + (u32)__popcll(a & ((1ull << lane) - 1ull));
      if (rank < KEEP_CAP) {
        int p = k * 1024 + tid;
        kept_key[g * KEEP_CAP + rank] = keys[p];
        kept_pos[g * KEEP_CAP + rank] = (u32)p;
      }
    }
  }
}

// ================= shared top-k / output =================
__global__ __launch_bounds__(512) void topk_kernel(
    const float* __restrict__ in, const u32* __restrict__ sorted_orig,
    const u64* __restrict__ alive_ws, const u32* __restrict__ kept_key,
    const u32* __restrict__ kept_pos, const u32* __restrict__ kept_cnt,
    float* __restrict__ out)
{
  const int b = blockIdx.x;
  const int tid = threadIdx.x;
  __shared__ u64 sk[2048];
  __shared__ int sT[3];
  if (tid < 3) sT[tid] = (int)kept_cnt[b * 3 + tid];
  __syncthreads();
  const int K0 = sT[0], K1 = sT[1], K2 = sT[2];
  const int Ttot = K0 + K1 + K2;

  for (int s = tid; s < 2048; s += 512) {
    u64 key = ~0ull;
    int c = s >> 9;
    if (c < NC) {
      int r = s & 511;
      int Kc = (c == 0) ? K0 : (c == 1) ? K1 : K2;
      if (r < min(Kc, KEEP_CAP)) {
        int g = b * 3 + c;
        u64 k32 = kept_key[g * KEEP_CAP + r];
        u32 pos = kept_pos[g * KEEP_CAP + r];
        key = (k32 << 15) | (u32)(c * NN + pos);
      }
    }
    sk[s] = key;
  }
  __syncthreads();
  for (int k = 2; k <= 2048; k <<= 1) {
    for (int j = k >> 1; j > 0; j >>= 1) {
      for (int t = tid; t < 1024; t += 512) {
        int i = (t << 1) - (t & (j - 1));
        int q = i | j;
        u64 ka = sk[i], kb = sk[q];
        bool up = ((i & k) == 0);
        if ((ka > kb) == up) { sk[i] = kb; sk[q] = ka; }
      }
      __syncthreads();
    }
  }
  const int navail = min(K0, KEEP_CAP) + min(K1, KEEP_CAP) + min(K2, KEEP_CAP);
  for (int r = tid; r < MAXN; r += 512) {
    int c, pos; float sval;
    if (r < navail) {
      u64 key = sk[r];
      u32 flat = (u32)(key & 32767u);
      c = (int)(flat >> 13); pos = (int)(flat & 8191);
      u32 k32 = (u32)(key >> 15);
      u32 o = ~k32;
      u32 bits = (o & 0x80000000u) ? (o ^ 0x80000000u) : ~o;
      sval = __uint_as_float(bits);
    } else {
      int need = r - Ttot;
      int fflat = 0;
      for (int wd = 0; wd < 384; ++wd) {
        u64 a = alive_ws[b * 384 + wd];
        int z = 64 - __popcll(a);
        if (need < z) {
          u64 na = ~a;
          for (int it = 0; it < need; ++it) na &= na - 1ull;
          fflat = wd * 64 + (__ffsll(na) - 1);
          break;
        }
        need -= z;
      }
      c = fflat >> 13; pos = fflat & 8191;
      sval = -INFINITY;
    }
    u32 orig = sorted_orig[(b * 3 + c) * NN + pos];
    const float* row = in + ((size_t)b * NN + orig) * 11;
    const float PI_F = 3.14159265358979323846f;
    float theta = row[6];
    float v = theta / PI_F;
    float fl = floorf(v + 1.0f);
    float lp = theta - fl * PI_F;
    float ang = lp + (1.0f - row[10]) * PI_F;
    float* ob = out + ((size_t)b * MAXN + r) * 7;
    ob[0] = row[0]; ob[1] = row[1]; ob[2] = row[2];
    ob[3] = row[3]; ob[4] = row[4]; ob[5] = row[5]; ob[6] = ang;
    out[NB * MAXN * 7 + b * MAXN + r] = (float)c;
    out[NB * MAXN * 7 + NB * MAXN + b * MAXN + r] = sval;
  }
}

extern "C" void kernel_launch(void* const* d_in, const int* in_sizes, int n_in,
                              void* d_out, int out_size, void* d_ws, size_t ws_size,
                              hipStream_t stream) {
  const float* in = (const float*)d_in[0];
  float* out = (float*)d_out;
  char* ws = (char*)d_ws;

  int P = 0;
  const int cands[6] = {12, 6, 4, 3, 2, 1};
  for (int ci = 0; ci < 6; ++ci) {
    if ((size_t)NMAT + (size_t)cands[ci] * MATB <= ws_size) { P = cands[ci]; break; }
  }

  if (P > 0) {
    u32* so = (u32*)(ws + NSO);
    u32* skey = (u32*)(ws + NSKEY);
    float4* sb4 = (float4*)(ws + NSB4);
    float* sar = (float*)(ws + NSAR);
    u64* valid = (u64*)(ws + NVAL);
    u64* alive = (u64*)(ws + NALV);
    u32* kkey = (u32*)(ws + NKKEY);
    u32* kpos = (u32*)(ws + NKPOS);
    u32* kcnt = (u32*)(ws + NKCNT);
    u32* flags = (u32*)(ws + NFLG);
    u64* pmat = (u64*)(ws + PMAT);
    u64* mat = (u64*)(ws + NMAT);

    sort_kernel<<<dim3(NG), dim3(1024), 0, stream>>>(
        in, so, skey, sb4, sar, valid);
    build_prefix_kernel<<<dim3(PB_BLOCKS), dim3(PB_TPB), 0, stream>>>(
        sb4, sar, pmat);
    scan_prefix_kernel<<<dim3(NG), dim3(1024), 0, stream>>>(
        pmat, valid, skey, kkey, kpos, kcnt, flags);
    for (int g0 = 0; g0 < NG; g0 += P) {
      build_kernel<<<dim3(BUILD_BLOCKS), dim3(BUILD_TPB), 0, stream>>>(
          sb4, sar, mat, flags, g0, P);
      scan_kernel<<<dim3(P), dim3(1024), 0, stream>>>(
          mat, valid, skey, alive, kkey, kpos, kcnt, flags, g0);
    }
    topk_kernel<<<dim3(NB), dim3(512), 0, stream>>>(
        in, so, alive, kkey, kpos, kcnt, out);
  } else {
    u32* sorted_orig = (u32*)(ws + WS_SORTED_ORIG);
    u64* alive = (u64*)(ws + WS_ALIVE);
    u32* kept_key = (u32*)(ws + WS_KEPT_KEY);
    u32* kept_pos = (u32*)(ws + WS_KEPT_POS);
    u32* kept_cnt = (u32*)(ws + WS_KEPT_CNT);
    nms_kernel<<<dim3(NG), dim3(1024), 0, stream>>>(
        in, sorted_orig, alive, kept_key, kept_pos, kept_cnt);
    topk_kernel<<<dim3(NB), dim3(512), 0, stream>>>(
        in, sorted_orig, alive, kept_key, kept_pos, kept_cnt, out);
  }
}

// Round 16
// 126.925 us; speedup vs baseline: 2.3556x; 1.1180x over previous
//
#include <hip/hip_runtime.h>
#include <stdint.h>

#pragma clang fp contract(off)

#define NB 4
#define NN 8192
#define NC 3
#define NG 12
#define MAXN 500
#define KEEP_CAP 512

typedef unsigned long long u64;
typedef uint32_t u32;
typedef uint16_t u16;

// ---------- ws layout (bytes) ----------
#define NSO   0u          // u32 [12][8192] sorted->orig
#define NSKEY 393216u     // u32 [12][8192] sorted key32
#define NSB4  786432u     // float4 [12][8192]
#define NSAR  2359296u    // f32 [12][8192]
#define NVAL  2752512u    // u64 [12][128] valid bits
#define NALV  2764800u    // u64 [12][128] keep bits
#define NKKEY 2777088u    // u32 [12][512]
#define NKPOS 2801664u    // u32 [12][512]
#define NKCNT 2826240u    // u32 [12]
#define NFLG  2826304u    // u32 [12] early-path flags
#define PMAT  3145728u    // u64 [12][32][2048] prefix matrix (6 MB), TRANSPOSED
                          // (also aliased as u64 kk[12][8192] during sort phase)
#define NMAT  9437184u    // full matrices start
#define MATB  8388608ull  // 8192*128*8 per problem

// prefix-NMS parameters
#define PR_CH   32        // 32 chunks of 64 = 2048 rows
#define PR_ROWS 2048
#define PUNITS_PER_G 528  // sum_{rb=0}^{31}(32-rb)
#define PB_TPB 256
#define PB_BLOCKS 1584    // 6336 waves = 12*528 units, 1/wave

// ---------- old-path (fallback) ws layout ----------
#define WS_SORTED_ORIG 0
#define WS_ALIVE       393216
#define WS_KEPT_KEY    405504
#define WS_KEPT_POS    430080
#define WS_KEPT_CNT    454656
#define NMS_EPS 1.0000004f

__device__ __forceinline__ u32 sort_key(float s) {
  u32 b = __float_as_uint(s);
  u32 o = (b & 0x80000000u) ? ~b : (b | 0x80000000u);
  return ~o;   // ascending key == descending float; -inf -> 0xFF800000
}

#define PHYS(i) ((i) + ((i) >> 3))
#define CEX(A, B, UP) \
  { if ((x[A] > x[B]) == (UP)) { u64 tt = x[A]; x[A] = x[B]; x[B] = tt; } }

// ========== sort stage 1: per-2048-segment full bitonic (through k=2048) ===
// grid 48 = 12 classes x 4 segments; 256 threads; direction from GLOBAL idx.
__global__ __launch_bounds__(256) void sortL_kernel(
    const float* __restrict__ in, u64* __restrict__ kk)
{
  const int g = blockIdx.x >> 2, seg = blockIdx.x & 3;
  const int b = g / NC, c = g % NC;
  const float* __restrict__ base = in + (size_t)b * NN * 11;
  __shared__ u64 sk[2304];             // PHYS(2047)+1, 18 KiB
  const int tid = threadIdx.x;
  const int gbase = seg << 11;

  for (int i = tid; i < 2048; i += 256) {
    int p = gbase + i;
    float sc = base[p * 11 + 7 + c];
    float s = (sc > 0.1f) ? sc : -INFINITY;
    sk[PHYS(i)] = ((u64)sort_key(s) << 16) | (u32)p;
  }
  __syncthreads();
  // pass 0: k=2,4,8 in registers (8 contiguous elems/thread)
  {
    const int pb = 9 * tid;
    u64 x[8];
#pragma unroll
    for (int a = 0; a < 8; ++a) x[a] = sk[pb + a];
    const bool u8 = (((gbase + (tid << 3)) & 8) == 0);
    CEX(0, 1, true); CEX(2, 3, false); CEX(4, 5, true); CEX(6, 7, false);
    CEX(0, 2, true); CEX(1, 3, true); CEX(4, 6, false); CEX(5, 7, false);
    CEX(0, 1, true); CEX(2, 3, true); CEX(4, 5, false); CEX(6, 7, false);
    CEX(0, 4, u8); CEX(1, 5, u8); CEX(2, 6, u8); CEX(3, 7, u8);
    CEX(0, 2, u8); CEX(1, 3, u8); CEX(4, 6, u8); CEX(5, 7, u8);
    CEX(0, 1, u8); CEX(2, 3, u8); CEX(4, 5, u8); CEX(6, 7, u8);
#pragma unroll
    for (int a = 0; a < 8; ++a) sk[pb + a] = x[a];
  }
  __syncthreads();
  for (int k = 16; k <= 2048; k <<= 1) {
    for (int j = k >> 1; j >= 8; j >>= 1) {
      for (int t = tid; t < 1024; t += 256) {
        int i = (t << 1) - (t & (j - 1));
        int q = i | j;
        int pi = PHYS(i), pq = PHYS(q);
        u64 ka = sk[pi], kb = sk[pq];
        bool up = (((gbase + i) & k) == 0);
        if ((ka > kb) == up) { sk[pi] = kb; sk[pq] = ka; }
      }
      __syncthreads();
    }
    {
      const int lb = tid << 3;
      const bool up = (((gbase + lb) & k) == 0);
      const int pb = 9 * tid;
      u64 x[8];
#pragma unroll
      for (int a = 0; a < 8; ++a) x[a] = sk[pb + a];
      CEX(0, 4, up); CEX(1, 5, up); CEX(2, 6, up); CEX(3, 7, up);
      CEX(0, 2, up); CEX(1, 3, up); CEX(4, 6, up); CEX(5, 7, up);
      CEX(0, 1, up); CEX(2, 3, up); CEX(4, 5, up); CEX(6, 7, up);
#pragma unroll
      for (int a = 0; a < 8; ++a) sk[pb + a] = x[a];
    }
    __syncthreads();
  }
  for (int i = tid; i < 2048; i += 256)
    kk[(size_t)g * NN + gbase + i] = sk[PHYS(i)];
}

// ========== sort stage 2: k=4096 level (j=2048..1) inside 4096-elem tile ===
// grid 24 = 12 x 2 pairs; 512 threads; direction uniform per block.
__global__ __launch_bounds__(512) void sortX1_kernel(u64* __restrict__ kk)
{
  const int g = blockIdx.x >> 1, pr = blockIdx.x & 1;
  const size_t off = (size_t)g * NN + pr * 4096;
  __shared__ u64 sk[4608];             // PHYS(4095)+1, 36 KiB
  const int tid = threadIdx.x;
  const bool up = (pr == 0);

  for (int i = tid; i < 4096; i += 512) sk[PHYS(i)] = kk[off + i];
  __syncthreads();
  for (int j = 2048; j >= 8; j >>= 1) {
    for (int t = tid; t < 2048; t += 512) {
      int i = (t << 1) - (t & (j - 1));
      int q = i | j;
      int pi = PHYS(i), pq = PHYS(q);
      u64 ka = sk[pi], kb = sk[pq];
      if ((ka > kb) == up) { sk[pi] = kb; sk[pq] = ka; }
    }
    __syncthreads();
  }
  {
    const int pb = 9 * tid;
    u64 x[8];
#pragma unroll
    for (int a = 0; a < 8; ++a) x[a] = sk[pb + a];
    CEX(0, 4, up); CEX(1, 5, up); CEX(2, 6, up); CEX(3, 7, up);
    CEX(0, 2, up); CEX(1, 3, up); CEX(4, 6, up); CEX(5, 7, up);
    CEX(0, 1, up); CEX(2, 3, up); CEX(4, 5, up); CEX(6, 7, up);
#pragma unroll
    for (int a = 0; a < 8; ++a) sk[pb + a] = x[a];
  }
  __syncthreads();
  for (int i = tid; i < 4096; i += 512) kk[off + i] = sk[PHYS(i)];
}

// ========== sort stage 3: k=8192, j=4096 global compare-exchange ===========
__global__ __launch_bounds__(1024) void sortX2_kernel(u64* __restrict__ kk)
{
  const int g = blockIdx.x >> 2;
  const int i = ((blockIdx.x & 3) << 10) + threadIdx.x;   // 0..4095
  u64* p = kk + (size_t)g * NN;
  u64 a = p[i], b = p[i + 4096];
  if (a > b) { p[i] = b; p[i + 4096] = a; }               // ascending
}

// ========== sort stage 4: k=8192 tail (j=2048..1) + epilogue ===============
__global__ __launch_bounds__(512) void sortX3_kernel(
    const float* __restrict__ in, u64* __restrict__ kk, u32* __restrict__ so,
    u32* __restrict__ skey, float4* __restrict__ sb4, float* __restrict__ sar,
    u64* __restrict__ valid)
{
  const int g = blockIdx.x >> 1, half = blockIdx.x & 1;
  const int b = g / NC;
  const size_t off = (size_t)g * NN + half * 4096;
  const int pbase = half * 4096;
  __shared__ u64 sk[4608];
  const int tid = threadIdx.x;

  for (int i = tid; i < 4096; i += 512) sk[PHYS(i)] = kk[off + i];
  __syncthreads();
  for (int j = 2048; j >= 8; j >>= 1) {
    for (int t = tid; t < 2048; t += 512) {
      int i = (t << 1) - (t & (j - 1));
      int q = i | j;
      int pi = PHYS(i), pq = PHYS(q);
      u64 ka = sk[pi], kb = sk[pq];
      if (ka > kb) { sk[pi] = kb; sk[pq] = ka; }          // ascending
    }
    __syncthreads();
  }
  {
    const int pb = 9 * tid;
    u64 x[8];
#pragma unroll
    for (int a = 0; a < 8; ++a) x[a] = sk[pb + a];
    CEX(0, 4, true); CEX(1, 5, true); CEX(2, 6, true); CEX(3, 7, true);
    CEX(0, 2, true); CEX(1, 3, true); CEX(4, 6, true); CEX(5, 7, true);
    CEX(0, 1, true); CEX(2, 3, true); CEX(4, 5, true); CEX(6, 7, true);
#pragma unroll
    for (int a = 0; a < 8; ++a) sk[pb + a] = x[a];
  }
  __syncthreads();

  const float* __restrict__ base = in + (size_t)b * NN * 11;
  const int lane = tid & 63;
#pragma unroll
  for (int it = 0; it < 8; ++it) {
    int i = it * 512 + tid;
    int p = pbase + i;
    u64 kv = sk[PHYS(i)];
    int orig = (int)(kv & 0xFFFFu);
    u32 key32 = (u32)(kv >> 16);
    so[(size_t)g * NN + p] = (u32)orig;
    skey[(size_t)g * NN + p] = key32;
    const float* r = base + orig * 11;
    float x = r[0], y = r[1], l = r[3], wd = r[4];
    float hx = l * 0.5f, hy = wd * 0.5f;
    float x1 = x - hx, y1 = y - hy, x2 = x + hx, y2 = y + hy;
    sb4[(size_t)g * NN + p] = make_float4(x1, y1, x2, y2);
    sar[(size_t)g * NN + p] = (x2 - x1) * (y2 - y1);
    u64 bal = __ballot(key32 != 0xFF800000u);
    if (lane == 0) valid[g * 128 + (p >> 6)] = bal;
  }
}

// ================= prefix build: rows 0..2047 x words 0..31 (upper tri) ====
__global__ __launch_bounds__(PB_TPB) void build_prefix_kernel(
    const float4* __restrict__ sb4, const float* __restrict__ sar,
    u64* __restrict__ pmat)
{
  const int wib = __builtin_amdgcn_readfirstlane((int)(threadIdx.x >> 6));
  const int lane = threadIdx.x & 63;
  const int W = blockIdx.x * (PB_TPB / 64) + wib;
  if (W >= NG * PUNITS_PER_G) return;
  const int g = W / PUNITS_PER_G;
  int r = W - g * PUNITS_PER_G;
  int rb = 0, cum = 0;
  while (r >= cum + (PR_CH - rb)) { cum += PR_CH - rb; ++rb; }
  const int jw = rb + (r - cum);
  const double CMULT = 0.25 * (1.0 + 0x1p-24);   // exact in double

  const int col = jw * 64 + lane;
  const float4 J = sb4[(size_t)g * NN + col];
  const float jar = sar[(size_t)g * NN + col];
  const float4* __restrict__ Ib = sb4 + (size_t)g * NN + rb * 64;
  const float* __restrict__ Ia = sar + (size_t)g * NN + rb * 64;

  u32 accLo = 0, accHi = 0;
  for (int rr = 0; rr < 64; ++rr) {
    const float4 I = Ib[rr];            // uniform -> s_load
    const float iar = Ia[rr];
    const bool sel = (lane == rr);
    float iw = fminf(I.z, J.z) - fmaxf(I.x, J.x);
    float ih = fminf(I.w, J.w) - fmaxf(I.y, J.y);
    iw = fmaxf(iw, 0.0f); ih = fmaxf(ih, 0.0f);
    float inter = iw * ih;
    float denom = ((iar + jar) - inter) + 1e-8f;
    u64 cand = __ballot((double)inter > CMULT * (double)denom);
    accLo = sel ? (u32)(cand & 0xffffffffu) : accLo;
    accHi = sel ? (u32)(cand >> 32) : accHi;
  }
  pmat[((size_t)(g * PR_CH + jw)) * PR_ROWS + rb * 64 + lane] =
      ((u64)accHi << 32) | accLo;
}

// ======= prefix scan (r15: fixpoint resolve + early exit) ==================
__global__ __launch_bounds__(1024) void scan_prefix_kernel(
    const u64* __restrict__ pmat, const u64* __restrict__ valid,
    const u32* __restrict__ skey, u32* __restrict__ kept_key,
    u32* __restrict__ kept_pos, u32* __restrict__ kept_cnt,
    u32* __restrict__ flags)
{
  const int g = blockIdx.x;
  const int tid = threadIdx.x;
  const int wv = tid >> 6, lane = tid & 63;
  const int wl = tid & 127, grp = tid >> 7;
  __shared__ u64 remv[PR_CH];
  __shared__ u64 keepw[PR_CH];
  __shared__ u64 keepS;
  __shared__ u32 prefixL[PR_CH];
  __shared__ u32 cntS;
  __shared__ int stopS;

  if (tid < PR_CH) { remv[tid] = ~valid[g * 128 + tid]; keepw[tid] = 0; }
  if (tid == 0) { cntS = 0; stopS = 0; }
  __syncthreads();

  const u64* __restrict__ pm = pmat + (size_t)g * PR_CH * PR_ROWS;
  u64 rwDiag = 0, rwDiagNext = 0;
  if (wv == 0) rwDiag = pm[lane];       // word 0, rows 0..63
  const u64 maskgt = (lane == 63) ? 0ull : (~0ull << (lane + 1));

  for (int cc = 0; cc < PR_CH; ++cc) {
    const int w = cc + 1 + wl;
    const bool act = (w < PR_CH);
    u64 rw[8];
    if (act) {
#pragma unroll
      for (int k = 0; k < 8; ++k)
        rw[k] = pm[(size_t)w * PR_ROWS + cc * 64 + grp * 8 + k];
    }
    if (wv == 0) {
      const u64 alive0 = ~remv[cc];
      u64 K = alive0;
      for (int it = 0; it < 64; ++it) {
        u64 contrib = ((K >> lane) & 1ull) ? (rwDiag & maskgt) : 0ull;
#pragma unroll
        for (int off = 32; off > 0; off >>= 1)
          contrib |= (u64)__shfl_xor((long long)contrib, off);
        u64 Knew = alive0 & ~contrib;
        if (Knew == K) break;
        K = Knew;
      }
      if (lane == 0) {
        keepw[cc] = K; keepS = K;
        cntS += (u32)__popcll(K);
        if (cntS >= KEEP_CAP) stopS = 1;
      }
      if (cc + 1 < PR_CH)
        rwDiagNext = pm[(size_t)(cc + 1) * PR_ROWS + (cc + 1) * 64 + lane];
    }
    __syncthreads();
    if (stopS) break;                    // uniform (read after barrier)
    if (act) {
      const u32 kmg = (u32)((keepS >> (grp * 8)) & 0xffu);
      u64 acc = 0;
#pragma unroll
      for (int k = 0; k < 8; ++k)
        if ((kmg >> k) & 1u) acc |= rw[k];
      if (acc) atomicOr(&remv[w], acc);
    }
    if (wv == 0) rwDiag = rwDiagNext;
    __syncthreads();
  }
  __syncthreads();

  if (tid == 0) {
    u32 acc = 0;
    for (int i = 0; i < PR_CH; ++i) { prefixL[i] = acc; acc += (u32)__popcll(keepw[i]); }
    cntS = acc;
    u32 ok = (acc >= KEEP_CAP) ? 1u : 0u;
    flags[g] = ok;
    if (ok) kept_cnt[g] = KEEP_CAP;
  }
  __syncthreads();
  if (cntS < KEEP_CAP) return;          // full path will handle this class
  for (int p = tid; p < PR_ROWS; p += 1024) {
    int wd = p >> 6;
    u64 kw = keepw[wd];
    if ((kw >> (p & 63)) & 1ull) {
      u32 rank = prefixL[wd] + (u32)__popcll(kw & ((1ull << (p & 63)) - 1ull));
      if (rank < KEEP_CAP) {
        kept_key[g * KEEP_CAP + rank] = skey[g * NN + p];
        kept_pos[g * KEEP_CAP + rank] = (u32)p;
      }
    }
  }
}

// ================= full path (flag-gated fallback; r10 build) =============
#define UNITS_PER_G 1088
#define BUILD_TPB 256
#define BUILD_BLOCKS 1632

__global__ __launch_bounds__(BUILD_TPB) void build_kernel(
    const float4* __restrict__ sb4, const float* __restrict__ sar,
    u64* __restrict__ mat, const u32* __restrict__ flags, int g0, int P)
{
  const int wib = __builtin_amdgcn_readfirstlane((int)(threadIdx.x >> 6));
  const int lane = threadIdx.x & 63;
  const int W = blockIdx.x * (BUILD_TPB / 64) + wib;
  const int NUNITS = P * UNITS_PER_G;
  const double CMULT = 0.25 * (1.0 + 0x1p-24);

  for (int u = W; u < NUNITS; u += BUILD_BLOCKS * (BUILD_TPB / 64)) {
    const int gp = u / UNITS_PER_G;
    if (flags[g0 + gp]) continue;       // early path already solved this class
    int r = u - gp * UNITS_PER_G;
    int rb8 = 0, cum = 0;
    while (r >= cum + 8 * (16 - rb8)) { cum += 8 * (16 - rb8); ++rb8; }
    const int idx = r - cum;
    const int nb = 16 - rb8;
    const int rb = rb8 * 8 + idx / nb;
    const int jb = rb8 + idx % nb;

    const int g = g0 + gp;
    float jx1[8], jy1[8], jx2[8], jy2[8], jar[8];
#pragma unroll
    for (int wq = 0; wq < 8; ++wq) {
      const int col = jb * 512 + wq * 64 + lane;
      const float4 J = sb4[(size_t)g * NN + col];
      jx1[wq] = J.x; jy1[wq] = J.y; jx2[wq] = J.z; jy2[wq] = J.w;
      jar[wq] = sar[(size_t)g * NN + col];
    }
    u32 accLo[8], accHi[8];
#pragma unroll
    for (int wq = 0; wq < 8; ++wq) { accLo[wq] = 0u; accHi[wq] = 0u; }

    const float4* __restrict__ Ib = sb4 + (size_t)g * NN + rb * 64;
    const float* __restrict__ Ia = sar + (size_t)g * NN + rb * 64;

    for (int rr = 0; rr < 64; ++rr) {
      const float4 I = Ib[rr];
      const float iar = Ia[rr];
      const bool sel = (lane == rr);
#pragma unroll
      for (int wq = 0; wq < 8; ++wq) {
        float iw = fminf(I.z, jx2[wq]) - fmaxf(I.x, jx1[wq]);
        float ih = fminf(I.w, jy2[wq]) - fmaxf(I.y, jy1[wq]);
        iw = fmaxf(iw, 0.0f); ih = fmaxf(ih, 0.0f);
        float inter = iw * ih;
        float denom = ((iar + jar[wq]) - inter) + 1e-8f;
        u64 cand = __ballot((double)inter > CMULT * (double)denom);
        accLo[wq] = sel ? (u32)(cand & 0xffffffffu) : accLo[wq];
        accHi[wq] = sel ? (u32)(cand >> 32) : accHi[wq];
      }
    }
    u64* dst = mat + ((size_t)(gp * NN + rb * 64 + lane)) * 128 + jb * 8;
    uint4* d4 = (uint4*)dst;
    d4[0] = make_uint4(accLo[0], accHi[0], accLo[1], accHi[1]);
    d4[1] = make_uint4(accLo[2], accHi[2], accLo[3], accHi[3]);
    d4[2] = make_uint4(accLo[4], accHi[4], accLo[5], accHi[5]);
    d4[3] = make_uint4(accLo[6], accHi[6], accLo[7], accHi[7]);
  }
}

__global__ __launch_bounds__(1024) void scan_kernel(
    const u64* __restrict__ mat, const u64* __restrict__ valid,
    const u32* __restrict__ skey, u64* __restrict__ alive_out,
    u32* __restrict__ kept_key, u32* __restrict__ kept_pos,
    u32* __restrict__ kept_cnt, const u32* __restrict__ flags, int g0)
{
  const int gp = blockIdx.x, g = g0 + gp;
  if (flags[g]) return;
  const int tid = threadIdx.x;
  const int wv = tid >> 6, lane = tid & 63;
  const int wl = tid & 127, grp = tid >> 7;
  __shared__ u64 remv[128];
  __shared__ u64 keepw[128];
  __shared__ u64 keepS;
  __shared__ u32 prefixL[128];

  if (tid < 128) remv[tid] = ~valid[g * 128 + tid];
  __syncthreads();

  const u64* __restrict__ pm = mat + (size_t)gp * NN * 128;
  u64 rwDiag = 0, rwDiagNext = 0;
  if (wv == 0) rwDiag = pm[((size_t)lane) * 128 + 0];

  for (int cc = 0; cc < 128; ++cc) {
    const int w = cc + 1 + wl;
    const bool act = (w < 128);
    u64 rw[8];
    if (act) {
#pragma unroll
      for (int k = 0; k < 8; ++k)
        rw[k] = pm[((size_t)(cc * 64 + grp * 8 + k)) * 128 + w];
    }
    if (wv == 0) {
      u64 m = ~remv[cc];
      u64 keepm = 0;
      while (m) {
        int bp = __ffsll(m) - 1;
        keepm |= 1ull << bp;
        m &= ~(1ull << bp);
        u32 rlo = (u32)__builtin_amdgcn_readlane((int)(u32)(rwDiag & 0xffffffffu), bp);
        u32 rhi = (u32)__builtin_amdgcn_readlane((int)(u32)(rwDiag >> 32), bp);
        m &= ~(((u64)rhi << 32) | rlo);
      }
      if (lane == 0) { keepw[cc] = keepm; keepS = keepm; }
      if (cc + 1 < 128) rwDiagNext = pm[((size_t)((cc + 1) * 64 + lane)) * 128 + (cc + 1)];
    }
    __syncthreads();
    if (act) {
      const u32 kmg = (u32)((keepS >> (grp * 8)) & 0xffu);
      u64 acc = 0;
#pragma unroll
      for (int k = 0; k < 8; ++k)
        if ((kmg >> k) & 1u) acc |= rw[k];
      if (acc) atomicOr(&remv[w], acc);
    }
    if (wv == 0) rwDiag = rwDiagNext;
    __syncthreads();
  }

  if (tid == 0) {
    u32 acc = 0;
    for (int i = 0; i < 128; ++i) { prefixL[i] = acc; acc += (u32)__popcll(keepw[i]); }
    kept_cnt[g] = acc;
  }
  __syncthreads();
  if (tid < 128) alive_out[g * 128 + tid] = keepw[tid];
  for (int p = tid; p < NN; p += 1024) {
    int wd = p >> 6;
    u64 kw = keepw[wd];
    if ((kw >> (p & 63)) & 1ull) {
      u32 rank = prefixL[wd] + (u32)__popcll(kw & ((1ull << (p & 63)) - 1ull));
      if (rank < KEEP_CAP) {
        kept_key[g * KEEP_CAP + rank] = skey[g * NN + p];
        kept_pos[g * KEEP_CAP + rank] = (u32)p;
      }
    }
  }
}

// ================= old path (fallback when ws too small, r2) ==============
__global__ __launch_bounds__(1024) void nms_kernel(
    const float* __restrict__ in, u32* __restrict__ sorted_orig,
    u64* __restrict__ alive_out, u32* __restrict__ kept_key,
    u32* __restrict__ kept_pos, u32* __restrict__ kept_cnt)
{
  const int g = blockIdx.x;
  const int b = g / NC, c = g % NC;
  const float* __restrict__ base = in + (size_t)b * NN * 11;
  __shared__ u32 keys[NN];
  __shared__ uint16_t sidx[NN];
  __shared__ float4 keeperBuf[2][64];
  __shared__ int nkBuf[2];
  __shared__ u64 aliveArr[128];
  __shared__ u32 prefix[128];
  const int tid = threadIdx.x;
  const int w = tid >> 6, lane = tid & 63;

  for (int p = tid; p < NN; p += 1024) {
    float sc = base[p * 11 + 7 + c];
    float s = (sc > 0.1f) ? sc : -INFINITY;
    keys[p] = sort_key(s);
    sidx[p] = (uint16_t)p;
  }
  __syncthreads();
  for (int k = 2; k <= NN; k <<= 1) {
    for (int j = k >> 1; j > 0; j >>= 1) {
      for (int t = tid; t < NN / 2; t += 1024) {
        int i = (t << 1) - (t & (j - 1));
        int q = i | j;
        u32 ka = keys[i], kb = keys[q];
        uint16_t ia = sidx[i], ib = sidx[q];
        bool gt = (ka > kb) || (ka == kb && ia > ib);
        bool up = ((i & k) == 0);
        if (gt == up) { keys[i] = kb; keys[q] = ka; sidx[i] = ib; sidx[q] = ia; }
      }
      __syncthreads();
    }
  }
  float bx1[8], by1[8], bx2[8], by2[8], barea[8];
  u64 alive[8];
#pragma unroll
  for (int k = 0; k < 8; ++k) {
    int p = k * 1024 + tid;
    u32 key = keys[p];
    int orig = sidx[p];
    sorted_orig[g * NN + p] = (u32)orig;
    const float* r = base + orig * 11;
    float x = r[0], y = r[1], l = r[3], wd = r[4];
    float hx = l * 0.5f, hy = wd * 0.5f;
    bx1[k] = x - hx; by1[k] = y - hy; bx2[k] = x + hx; by2[k] = y + hy;
    barea[k] = (bx2[k] - bx1[k]) * (by2[k] - by1[k]);
    alive[k] = __ballot(key != 0xFF800000u);
  }
  for (int cc = 0; cc < 128; ++cc) {
    __syncthreads();
    int nk_prev = (cc > 0) ? nkBuf[(cc - 1) & 1] : 0;
    if (nk_prev > 0) {
      const int par = (cc - 1) & 1;
      for (int j = 0; j < nk_prev; ++j) {
        float4 K = keeperBuf[par][j];
        float ka = (K.z - K.x) * (K.w - K.y);
#pragma unroll
        for (int k = 0; k < 8; ++k) {
          if ((k * 16 + w) < cc) continue;
          if (alive[k] == 0ull) continue;
          float iw = fminf(bx2[k], K.z) - fmaxf(bx1[k], K.x);
          float ih = fminf(by2[k], K.w) - fmaxf(by1[k], K.y);
          iw = fmaxf(iw, 0.0f); ih = fmaxf(ih, 0.0f);
          float inter = iw * ih;
          float denom = (barea[k] + ka) - inter + 1e-8f;
          float t = 0.25f * denom;
          u64 sup = __ballot(inter > t);
          u64 wnd = __ballot(inter > t && inter <= t * NMS_EPS);
          if (wnd) {
            bool bb = inter > t;
            if (bb && inter <= t * NMS_EPS) bb = (inter / denom) > 0.25f;
            sup = __ballot(bb);
          }
          alive[k] &= ~sup;
        }
      }
    }
    if (w == (cc & 15)) {
      float mx1 = 0.f, my1 = 0.f, mx2 = 0.f, my2 = 0.f, ma = 0.f;
      u64 m = 0ull;
#pragma unroll
      for (int k = 0; k < 8; ++k) if (k == (cc >> 4)) {
        mx1 = bx1[k]; my1 = by1[k]; mx2 = bx2[k]; my2 = by2[k]; ma = barea[k];
        m = alive[k];
      }
      u64 keepm = 0ull;
      int nk = 0;
      while (m) {
        int bp = __ffsll(m) - 1;
        keepm |= 1ull << bp;
        m &= ~(1ull << bp);
        float kx1 = __shfl(mx1, bp), ky1 = __shfl(my1, bp);
        float kx2 = __shfl(mx2, bp), ky2 = __shfl(my2, bp);
        float ka = (kx2 - kx1) * (ky2 - ky1);
        float iw = fminf(mx2, kx2) - fmaxf(mx1, kx1);
        float ih = fminf(my2, ky2) - fmaxf(my1, ky1);
        iw = fmaxf(iw, 0.0f); ih = fmaxf(ih, 0.0f);
        float inter = iw * ih;
        float denom = (ma + ka) - inter + 1e-8f;
        float t = 0.25f * denom;
        u64 sup = __ballot(inter > t);
        u64 wnd = __ballot(inter > t && inter <= t * NMS_EPS);
        if (wnd) {
          bool bb = inter > t;
          if (bb && inter <= t * NMS_EPS) bb = (inter / denom) > 0.25f;
          sup = __ballot(bb);
        }
        m &= ~sup;
        if (lane == bp) keeperBuf[cc & 1][nk] = make_float4(mx1, my1, mx2, my2);
        nk++;
      }
#pragma unroll
      for (int k = 0; k < 8; ++k) if (k == (cc >> 4)) alive[k] = keepm;
      if (lane == 0) nkBuf[cc & 1] = nk;
    }
  }
  __syncthreads();
  if (lane == 0) {
#pragma unroll
    for (int k = 0; k < 8; ++k) aliveArr[k * 16 + w] = alive[k];
  }
  __syncthreads();
  if (tid == 0) {
    u32 acc = 0;
    for (int i = 0; i < 128; ++i) { prefix[i] = acc; acc += (u32)__popcll(aliveArr[i]); }
    kept_cnt[g] = acc;
  }
  __syncthreads();
  for (int i = tid; i < 128; i += 1024) alive_out[g * 128 + i] = aliveArr[i];
#pragma unroll
  for (int k = 0; k < 8; ++k) {
    int word = k * 16 + w;
    u64 a = alive[k];
    if ((a >> lane) & 1ull) {
      u32 rank = prefix[word] + (u32)__popcll(a & ((1ull << lane) - 1ull));
      if (rank < KEEP_CAP) {
        int p = k * 1024 + tid;
        kept_key[g * KEEP_CAP + rank] = keys[p];
        kept_pos[g * KEEP_CAP + rank] = (u32)p;
      }
    }
  }
}

// ================= shared top-k / output =================
__global__ __launch_bounds__(512) void topk_kernel(
    const float* __restrict__ in, const u32* __restrict__ sorted_orig,
    const u64* __restrict__ alive_ws, const u32* __restrict__ kept_key,
    const u32* __restrict__ kept_pos, const u32* __restrict__ kept_cnt,
    float* __restrict__ out)
{
  const int b = blockIdx.x;
  const int tid = threadIdx.x;
  __shared__ u64 sk[2048];
  __shared__ int sT[3];
  if (tid < 3) sT[tid] = (int)kept_cnt[b * 3 + tid];
  __syncthreads();
  const int K0 = sT[0], K1 = sT[1], K2 = sT[2];
  const int Ttot = K0 + K1 + K2;

  for (int s = tid; s < 2048; s += 512) {
    u64 key = ~0ull;
    int c = s >> 9;
    if (c < NC) {
      int r = s & 511;
      int Kc = (c == 0) ? K0 : (c == 1) ? K1 : K2;
      if (r < min(Kc, KEEP_CAP)) {
        int g = b * 3 + c;
        u64 k32 = kept_key[g * KEEP_CAP + r];
        u32 pos = kept_pos[g * KEEP_CAP + r];
        key = (k32 << 15) | (u32)(c * NN + pos);
      }
    }
    sk[s] = key;
  }
  __syncthreads();
  for (int k = 2; k <= 2048; k <<= 1) {
    for (int j = k >> 1; j > 0; j >>= 1) {
      for (int t = tid; t < 1024; t += 512) {
        int i = (t << 1) - (t & (j - 1));
        int q = i | j;
        u64 ka = sk[i], kb = sk[q];
        bool up = ((i & k) == 0);
        if ((ka > kb) == up) { sk[i] = kb; sk[q] = ka; }
      }
      __syncthreads();
    }
  }
  const int navail = min(K0, KEEP_CAP) + min(K1, KEEP_CAP) + min(K2, KEEP_CAP);
  for (int r = tid; r < MAXN; r += 512) {
    int c, pos; float sval;
    if (r < navail) {
      u64 key = sk[r];
      u32 flat = (u32)(key & 32767u);
      c = (int)(flat >> 13); pos = (int)(flat & 8191);
      u32 k32 = (u32)(key >> 15);
      u32 o = ~k32;
      u32 bits = (o & 0x80000000u) ? (o ^ 0x80000000u) : ~o;
      sval = __uint_as_float(bits);
    } else {
      int need = r - Ttot;
      int fflat = 0;
      for (int wd = 0; wd < 384; ++wd) {
        u64 a = alive_ws[b * 384 + wd];
        int z = 64 - __popcll(a);
        if (need < z) {
          u64 na = ~a;
          for (int it = 0; it < need; ++it) na &= na - 1ull;
          fflat = wd * 64 + (__ffsll(na) - 1);
          break;
        }
        need -= z;
      }
      c = fflat >> 13; pos = fflat & 8191;
      sval = -INFINITY;
    }
    u32 orig = sorted_orig[(b * 3 + c) * NN + pos];
    const float* row = in + ((size_t)b * NN + orig) * 11;
    const float PI_F = 3.14159265358979323846f;
    float theta = row[6];
    float v = theta / PI_F;
    float fl = floorf(v + 1.0f);
    float lp = theta - fl * PI_F;
    float ang = lp + (1.0f - row[10]) * PI_F;
    float* ob = out + ((size_t)b * MAXN + r) * 7;
    ob[0] = row[0]; ob[1] = row[1]; ob[2] = row[2];
    ob[3] = row[3]; ob[4] = row[4]; ob[5] = row[5]; ob[6] = ang;
    out[NB * MAXN * 7 + b * MAXN + r] = (float)c;
    out[NB * MAXN * 7 + NB * MAXN + b * MAXN + r] = sval;
  }
}

extern "C" void kernel_launch(void* const* d_in, const int* in_sizes, int n_in,
                              void* d_out, int out_size, void* d_ws, size_t ws_size,
                              hipStream_t stream) {
  const float* in = (const float*)d_in[0];
  float* out = (float*)d_out;
  char* ws = (char*)d_ws;

  int P = 0;
  const int cands[6] = {12, 6, 4, 3, 2, 1};
  for (int ci = 0; ci < 6; ++ci) {
    if ((size_t)NMAT + (size_t)cands[ci] * MATB <= ws_size) { P = cands[ci]; break; }
  }

  if (P > 0) {
    u32* so = (u32*)(ws + NSO);
    u32* skey = (u32*)(ws + NSKEY);
    float4* sb4 = (float4*)(ws + NSB4);
    float* sar = (float*)(ws + NSAR);
    u64* valid = (u64*)(ws + NVAL);
    u64* alive = (u64*)(ws + NALV);
    u32* kkey = (u32*)(ws + NKKEY);
    u32* kpos = (u32*)(ws + NKPOS);
    u32* kcnt = (u32*)(ws + NKCNT);
    u32* flags = (u32*)(ws + NFLG);
    u64* pmat = (u64*)(ws + PMAT);
    u64* kk = (u64*)(ws + PMAT);        // alias: dead before build_prefix runs
    u64* mat = (u64*)(ws + NMAT);

    sortL_kernel<<<dim3(48), dim3(256), 0, stream>>>(in, kk);
    sortX1_kernel<<<dim3(24), dim3(512), 0, stream>>>(kk);
    sortX2_kernel<<<dim3(48), dim3(1024), 0, stream>>>(kk);
    sortX3_kernel<<<dim3(24), dim3(512), 0, stream>>>(
        in, kk, so, skey, sb4, sar, valid);
    build_prefix_kernel<<<dim3(PB_BLOCKS), dim3(PB_TPB), 0, stream>>>(
        sb4, sar, pmat);
    scan_prefix_kernel<<<dim3(NG), dim3(1024), 0, stream>>>(
        pmat, valid, skey, kkey, kpos, kcnt, flags);
    for (int g0 = 0; g0 < NG; g0 += P) {
      build_kernel<<<dim3(BUILD_BLOCKS), dim3(BUILD_TPB), 0, stream>>>(
          sb4, sar, mat, flags, g0, P);
      scan_kernel<<<dim3(P), dim3(1024), 0, stream>>>(
          mat, valid, skey, alive, kkey, kpos, kcnt, flags, g0);
    }
    topk_kernel<<<dim3(NB), dim3(512), 0, stream>>>(
        in, so, alive, kkey, kpos, kcnt, out);
  } else {
    u32* sorted_orig = (u32*)(ws + WS_SORTED_ORIG);
    u64* alive = (u64*)(ws + WS_ALIVE);
    u32* kept_key = (u32*)(ws + WS_KEPT_KEY);
    u32* kept_pos = (u32*)(ws + WS_KEPT_POS);
    u32* kept_cnt = (u32*)(ws + WS_KEPT_CNT);
    nms_kernel<<<dim3(NG), dim3(1024), 0, stream>>>(
        in, sorted_orig, alive, kept_key, kept_pos, kept_cnt);
    topk_kernel<<<dim3(NB), dim3(512), 0, stream>>>(
        in, sorted_orig, alive, kept_key, kept_pos, kept_cnt, out);
  }
}

// Round 17
// 110.231 us; speedup vs baseline: 2.7123x; 1.1515x over previous
//
#include <hip/hip_runtime.h>
#include <stdint.h>

#pragma clang fp contract(off)

#define NB 4
#define NN 8192
#define NC 3
#define NG 12
#define MAXN 500
#define KEEP_CAP 512

typedef unsigned long long u64;
typedef uint32_t u32;
typedef uint16_t u16;

// ---------- ws layout (bytes) ----------
#define NSO   0u          // u32 [12][8192] sorted->orig
#define NSKEY 393216u     // u32 [12][8192] sorted key32
#define NSB4  786432u     // float4 [12][8192]
#define NSAR  2359296u    // f32 [12][8192]
#define NVAL  2752512u    // u64 [12][128] valid bits
#define NALV  2764800u    // u64 [12][128] keep bits
#define NKKEY 2777088u    // u32 [12][512]
#define NKPOS 2801664u    // u32 [12][512]
#define NKCNT 2826240u    // u32 [12]
#define NFLG  2826304u    // u32 [12] early-path flags
#define PMAT  3145728u    // u64 [12][32][2048] prefix matrix (6 MB), TRANSPOSED
                          // (also aliased as u64 kk[12][8192] during sort phase)
#define NMAT  9437184u    // full matrices start
#define MATB  8388608ull  // 8192*128*8 per problem

// prefix-NMS parameters
#define PR_CH   32        // 32 chunks of 64 = 2048 rows
#define PR_ROWS 2048
#define PUNITS_PER_G 528  // sum_{rb=0}^{31}(32-rb)
#define PB_TPB 256
#define PB_BLOCKS 1584    // 6336 waves = 12*528 units, 1/wave

// ---------- old-path (fallback) ws layout ----------
#define WS_SORTED_ORIG 0
#define WS_ALIVE       393216
#define WS_KEPT_KEY    405504
#define WS_KEPT_POS    430080
#define WS_KEPT_CNT    454656
#define NMS_EPS 1.0000004f

__device__ __forceinline__ u32 sort_key(float s) {
  u32 b = __float_as_uint(s);
  u32 o = (b & 0x80000000u) ? ~b : (b | 0x80000000u);
  return ~o;   // ascending key == descending float; -inf -> 0xFF800000
}

#define PHYS(i) ((i) + ((i) >> 3))
#define CEX(A, B, UP) \
  { if ((x[A] > x[B]) == (UP)) { u64 tt = x[A]; x[A] = x[B]; x[B] = tt; } }

// ========== sort stage 1: per-2048-segment full bitonic (through k=2048) ===
__global__ __launch_bounds__(256) void sortL_kernel(
    const float* __restrict__ in, u64* __restrict__ kk)
{
  const int g = blockIdx.x >> 2, seg = blockIdx.x & 3;
  const int b = g / NC, c = g % NC;
  const float* __restrict__ base = in + (size_t)b * NN * 11;
  __shared__ u64 sk[2304];             // PHYS(2047)+1, 18 KiB
  const int tid = threadIdx.x;
  const int gbase = seg << 11;

  for (int i = tid; i < 2048; i += 256) {
    int p = gbase + i;
    float sc = base[p * 11 + 7 + c];
    float s = (sc > 0.1f) ? sc : -INFINITY;
    sk[PHYS(i)] = ((u64)sort_key(s) << 16) | (u32)p;
  }
  __syncthreads();
  {
    const int pb = 9 * tid;
    u64 x[8];
#pragma unroll
    for (int a = 0; a < 8; ++a) x[a] = sk[pb + a];
    const bool u8 = (((gbase + (tid << 3)) & 8) == 0);
    CEX(0, 1, true); CEX(2, 3, false); CEX(4, 5, true); CEX(6, 7, false);
    CEX(0, 2, true); CEX(1, 3, true); CEX(4, 6, false); CEX(5, 7, false);
    CEX(0, 1, true); CEX(2, 3, true); CEX(4, 5, false); CEX(6, 7, false);
    CEX(0, 4, u8); CEX(1, 5, u8); CEX(2, 6, u8); CEX(3, 7, u8);
    CEX(0, 2, u8); CEX(1, 3, u8); CEX(4, 6, u8); CEX(5, 7, u8);
    CEX(0, 1, u8); CEX(2, 3, u8); CEX(4, 5, u8); CEX(6, 7, u8);
#pragma unroll
    for (int a = 0; a < 8; ++a) sk[pb + a] = x[a];
  }
  __syncthreads();
  for (int k = 16; k <= 2048; k <<= 1) {
    for (int j = k >> 1; j >= 8; j >>= 1) {
      for (int t = tid; t < 1024; t += 256) {
        int i = (t << 1) - (t & (j - 1));
        int q = i | j;
        int pi = PHYS(i), pq = PHYS(q);
        u64 ka = sk[pi], kb = sk[pq];
        bool up = (((gbase + i) & k) == 0);
        if ((ka > kb) == up) { sk[pi] = kb; sk[pq] = ka; }
      }
      __syncthreads();
    }
    {
      const int lb = tid << 3;
      const bool up = (((gbase + lb) & k) == 0);
      const int pb = 9 * tid;
      u64 x[8];
#pragma unroll
      for (int a = 0; a < 8; ++a) x[a] = sk[pb + a];
      CEX(0, 4, up); CEX(1, 5, up); CEX(2, 6, up); CEX(3, 7, up);
      CEX(0, 2, up); CEX(1, 3, up); CEX(4, 6, up); CEX(5, 7, up);
      CEX(0, 1, up); CEX(2, 3, up); CEX(4, 5, up); CEX(6, 7, up);
#pragma unroll
      for (int a = 0; a < 8; ++a) sk[pb + a] = x[a];
    }
    __syncthreads();
  }
  for (int i = tid; i < 2048; i += 256)
    kk[(size_t)g * NN + gbase + i] = sk[PHYS(i)];
}

// ========== sort stage 2: k=4096 level (j=2048..1) inside 4096-elem tile ===
__global__ __launch_bounds__(512) void sortX1_kernel(u64* __restrict__ kk)
{
  const int g = blockIdx.x >> 1, pr = blockIdx.x & 1;
  const size_t off = (size_t)g * NN + pr * 4096;
  __shared__ u64 sk[4608];             // PHYS(4095)+1, 36 KiB
  const int tid = threadIdx.x;
  const bool up = (pr == 0);

  for (int i = tid; i < 4096; i += 512) sk[PHYS(i)] = kk[off + i];
  __syncthreads();
  for (int j = 2048; j >= 8; j >>= 1) {
    for (int t = tid; t < 2048; t += 512) {
      int i = (t << 1) - (t & (j - 1));
      int q = i | j;
      int pi = PHYS(i), pq = PHYS(q);
      u64 ka = sk[pi], kb = sk[pq];
      if ((ka > kb) == up) { sk[pi] = kb; sk[pq] = ka; }
    }
    __syncthreads();
  }
  {
    const int pb = 9 * tid;
    u64 x[8];
#pragma unroll
    for (int a = 0; a < 8; ++a) x[a] = sk[pb + a];
    CEX(0, 4, up); CEX(1, 5, up); CEX(2, 6, up); CEX(3, 7, up);
    CEX(0, 2, up); CEX(1, 3, up); CEX(4, 6, up); CEX(5, 7, up);
    CEX(0, 1, up); CEX(2, 3, up); CEX(4, 5, up); CEX(6, 7, up);
#pragma unroll
    for (int a = 0; a < 8; ++a) sk[pb + a] = x[a];
  }
  __syncthreads();
  for (int i = tid; i < 4096; i += 512) kk[off + i] = sk[PHYS(i)];
}

// ========== sort stage 3: k=8192, j=4096 global compare-exchange ===========
__global__ __launch_bounds__(1024) void sortX2_kernel(u64* __restrict__ kk)
{
  const int g = blockIdx.x >> 2;
  const int i = ((blockIdx.x & 3) << 10) + threadIdx.x;   // 0..4095
  u64* p = kk + (size_t)g * NN;
  u64 a = p[i], b = p[i + 4096];
  if (a > b) { p[i] = b; p[i + 4096] = a; }               // ascending
}

// ========== sort stage 4: k=8192 tail (j=2048..1) + epilogue ===============
__global__ __launch_bounds__(512) void sortX3_kernel(
    const float* __restrict__ in, u64* __restrict__ kk, u32* __restrict__ so,
    u32* __restrict__ skey, float4* __restrict__ sb4, float* __restrict__ sar,
    u64* __restrict__ valid)
{
  const int g = blockIdx.x >> 1, half = blockIdx.x & 1;
  const int b = g / NC;
  const size_t off = (size_t)g * NN + half * 4096;
  const int pbase = half * 4096;
  __shared__ u64 sk[4608];
  const int tid = threadIdx.x;

  for (int i = tid; i < 4096; i += 512) sk[PHYS(i)] = kk[off + i];
  __syncthreads();
  for (int j = 2048; j >= 8; j >>= 1) {
    for (int t = tid; t < 2048; t += 512) {
      int i = (t << 1) - (t & (j - 1));
      int q = i | j;
      int pi = PHYS(i), pq = PHYS(q);
      u64 ka = sk[pi], kb = sk[pq];
      if (ka > kb) { sk[pi] = kb; sk[pq] = ka; }          // ascending
    }
    __syncthreads();
  }
  {
    const int pb = 9 * tid;
    u64 x[8];
#pragma unroll
    for (int a = 0; a < 8; ++a) x[a] = sk[pb + a];
    CEX(0, 4, true); CEX(1, 5, true); CEX(2, 6, true); CEX(3, 7, true);
    CEX(0, 2, true); CEX(1, 3, true); CEX(4, 6, true); CEX(5, 7, true);
    CEX(0, 1, true); CEX(2, 3, true); CEX(4, 5, true); CEX(6, 7, true);
#pragma unroll
    for (int a = 0; a < 8; ++a) sk[pb + a] = x[a];
  }
  __syncthreads();

  const float* __restrict__ base = in + (size_t)b * NN * 11;
  const int lane = tid & 63;
#pragma unroll
  for (int it = 0; it < 8; ++it) {
    int i = it * 512 + tid;
    int p = pbase + i;
    u64 kv = sk[PHYS(i)];
    int orig = (int)(kv & 0xFFFFu);
    u32 key32 = (u32)(kv >> 16);
    so[(size_t)g * NN + p] = (u32)orig;
    skey[(size_t)g * NN + p] = key32;
    const float* r = base + orig * 11;
    float x = r[0], y = r[1], l = r[3], wd = r[4];
    float hx = l * 0.5f, hy = wd * 0.5f;
    float x1 = x - hx, y1 = y - hy, x2 = x + hx, y2 = y + hy;
    sb4[(size_t)g * NN + p] = make_float4(x1, y1, x2, y2);
    sar[(size_t)g * NN + p] = (x2 - x1) * (y2 - y1);
    u64 bal = __ballot(key32 != 0xFF800000u);
    if (lane == 0) valid[g * 128 + (p >> 6)] = bal;
  }
}

// ================= prefix build: rows 0..2047 x words 0..31 (upper tri) ====
__global__ __launch_bounds__(PB_TPB) void build_prefix_kernel(
    const float4* __restrict__ sb4, const float* __restrict__ sar,
    u64* __restrict__ pmat)
{
  const int wib = __builtin_amdgcn_readfirstlane((int)(threadIdx.x >> 6));
  const int lane = threadIdx.x & 63;
  const int W = blockIdx.x * (PB_TPB / 64) + wib;
  if (W >= NG * PUNITS_PER_G) return;
  const int g = W / PUNITS_PER_G;
  int r = W - g * PUNITS_PER_G;
  int rb = 0, cum = 0;
  while (r >= cum + (PR_CH - rb)) { cum += PR_CH - rb; ++rb; }
  const int jw = rb + (r - cum);
  const double CMULT = 0.25 * (1.0 + 0x1p-24);   // exact in double

  const int col = jw * 64 + lane;
  const float4 J = sb4[(size_t)g * NN + col];
  const float jar = sar[(size_t)g * NN + col];
  const float4* __restrict__ Ib = sb4 + (size_t)g * NN + rb * 64;
  const float* __restrict__ Ia = sar + (size_t)g * NN + rb * 64;

  u32 accLo = 0, accHi = 0;
  for (int rr = 0; rr < 64; ++rr) {
    const float4 I = Ib[rr];            // uniform -> s_load
    const float iar = Ia[rr];
    const bool sel = (lane == rr);
    float iw = fminf(I.z, J.z) - fmaxf(I.x, J.x);
    float ih = fminf(I.w, J.w) - fmaxf(I.y, J.y);
    iw = fmaxf(iw, 0.0f); ih = fmaxf(ih, 0.0f);
    float inter = iw * ih;
    float denom = ((iar + jar) - inter) + 1e-8f;
    u64 cand = __ballot((double)inter > CMULT * (double)denom);
    accLo = sel ? (u32)(cand & 0xffffffffu) : accLo;
    accHi = sel ? (u32)(cand >> 32) : accHi;
  }
  pmat[((size_t)(g * PR_CH + jw)) * PR_ROWS + rb * 64 + lane] =
      ((u64)accHi << 32) | accLo;
}

// ======= prefix scan (r15: fixpoint resolve + early exit) ==================
__global__ __launch_bounds__(1024) void scan_prefix_kernel(
    const u64* __restrict__ pmat, const u64* __restrict__ valid,
    const u32* __restrict__ skey, u32* __restrict__ kept_key,
    u32* __restrict__ kept_pos, u32* __restrict__ kept_cnt,
    u32* __restrict__ flags)
{
  const int g = blockIdx.x;
  const int tid = threadIdx.x;
  const int wv = tid >> 6, lane = tid & 63;
  const int wl = tid & 127, grp = tid >> 7;
  __shared__ u64 remv[PR_CH];
  __shared__ u64 keepw[PR_CH];
  __shared__ u64 keepS;
  __shared__ u32 prefixL[PR_CH];
  __shared__ u32 cntS;
  __shared__ int stopS;

  if (tid < PR_CH) { remv[tid] = ~valid[g * 128 + tid]; keepw[tid] = 0; }
  if (tid == 0) { cntS = 0; stopS = 0; }
  __syncthreads();

  const u64* __restrict__ pm = pmat + (size_t)g * PR_CH * PR_ROWS;
  u64 rwDiag = 0, rwDiagNext = 0;
  if (wv == 0) rwDiag = pm[lane];       // word 0, rows 0..63
  const u64 maskgt = (lane == 63) ? 0ull : (~0ull << (lane + 1));

  for (int cc = 0; cc < PR_CH; ++cc) {
    const int w = cc + 1 + wl;
    const bool act = (w < PR_CH);
    u64 rw[8];
    if (act) {
#pragma unroll
      for (int k = 0; k < 8; ++k)
        rw[k] = pm[(size_t)w * PR_ROWS + cc * 64 + grp * 8 + k];
    }
    if (wv == 0) {
      const u64 alive0 = ~remv[cc];
      u64 K = alive0;
      for (int it = 0; it < 64; ++it) {
        u64 contrib = ((K >> lane) & 1ull) ? (rwDiag & maskgt) : 0ull;
#pragma unroll
        for (int off = 32; off > 0; off >>= 1)
          contrib |= (u64)__shfl_xor((long long)contrib, off);
        u64 Knew = alive0 & ~contrib;
        if (Knew == K) break;
        K = Knew;
      }
      if (lane == 0) {
        keepw[cc] = K; keepS = K;
        cntS += (u32)__popcll(K);
        if (cntS >= KEEP_CAP) stopS = 1;
      }
      if (cc + 1 < PR_CH)
        rwDiagNext = pm[(size_t)(cc + 1) * PR_ROWS + (cc + 1) * 64 + lane];
    }
    __syncthreads();
    if (stopS) break;                    // uniform (read after barrier)
    if (act) {
      const u32 kmg = (u32)((keepS >> (grp * 8)) & 0xffu);
      u64 acc = 0;
#pragma unroll
      for (int k = 0; k < 8; ++k)
        if ((kmg >> k) & 1u) acc |= rw[k];
      if (acc) atomicOr(&remv[w], acc);
    }
    if (wv == 0) rwDiag = rwDiagNext;
    __syncthreads();
  }
  __syncthreads();

  if (tid == 0) {
    u32 acc = 0;
    for (int i = 0; i < PR_CH; ++i) { prefixL[i] = acc; acc += (u32)__popcll(keepw[i]); }
    cntS = acc;
    u32 ok = (acc >= KEEP_CAP) ? 1u : 0u;
    flags[g] = ok;
    if (ok) kept_cnt[g] = KEEP_CAP;
  }
  __syncthreads();
  if (cntS < KEEP_CAP) return;          // full path will handle this class
  for (int p = tid; p < PR_ROWS; p += 1024) {
    int wd = p >> 6;
    u64 kw = keepw[wd];
    if ((kw >> (p & 63)) & 1ull) {
      u32 rank = prefixL[wd] + (u32)__popcll(kw & ((1ull << (p & 63)) - 1ull));
      if (rank < KEEP_CAP) {
        kept_key[g * KEEP_CAP + rank] = skey[g * NN + p];
        kept_pos[g * KEEP_CAP + rank] = (u32)p;
      }
    }
  }
}

// ================= full path (flag-gated fallback; r10 build) =============
#define UNITS_PER_G 1088
#define BUILD_TPB 256
#define BUILD_BLOCKS 816

__global__ __launch_bounds__(BUILD_TPB) void build_kernel(
    const float4* __restrict__ sb4, const float* __restrict__ sar,
    u64* __restrict__ mat, const u32* __restrict__ flags, int g0, int P)
{
  const int wib = __builtin_amdgcn_readfirstlane((int)(threadIdx.x >> 6));
  const int lane = threadIdx.x & 63;
  const int W = blockIdx.x * (BUILD_TPB / 64) + wib;
  const int NUNITS = P * UNITS_PER_G;
  const double CMULT = 0.25 * (1.0 + 0x1p-24);

  for (int u = W; u < NUNITS; u += BUILD_BLOCKS * (BUILD_TPB / 64)) {
    const int gp = u / UNITS_PER_G;
    if (flags[g0 + gp]) continue;       // early path already solved this class
    int r = u - gp * UNITS_PER_G;
    int rb8 = 0, cum = 0;
    while (r >= cum + 8 * (16 - rb8)) { cum += 8 * (16 - rb8); ++rb8; }
    const int idx = r - cum;
    const int nb = 16 - rb8;
    const int rb = rb8 * 8 + idx / nb;
    const int jb = rb8 + idx % nb;

    const int g = g0 + gp;
    float jx1[8], jy1[8], jx2[8], jy2[8], jar[8];
#pragma unroll
    for (int wq = 0; wq < 8; ++wq) {
      const int col = jb * 512 + wq * 64 + lane;
      const float4 J = sb4[(size_t)g * NN + col];
      jx1[wq] = J.x; jy1[wq] = J.y; jx2[wq] = J.z; jy2[wq] = J.w;
      jar[wq] = sar[(size_t)g * NN + col];
    }
    u32 accLo[8], accHi[8];
#pragma unroll
    for (int wq = 0; wq < 8; ++wq) { accLo[wq] = 0u; accHi[wq] = 0u; }

    const float4* __restrict__ Ib = sb4 + (size_t)g * NN + rb * 64;
    const float* __restrict__ Ia = sar + (size_t)g * NN + rb * 64;

    for (int rr = 0; rr < 64; ++rr) {
      const float4 I = Ib[rr];
      const float iar = Ia[rr];
      const bool sel = (lane == rr);
#pragma unroll
      for (int wq = 0; wq < 8; ++wq) {
        float iw = fminf(I.z, jx2[wq]) - fmaxf(I.x, jx1[wq]);
        float ih = fminf(I.w, jy2[wq]) - fmaxf(I.y, jy1[wq]);
        iw = fmaxf(iw, 0.0f); ih = fmaxf(ih, 0.0f);
        float inter = iw * ih;
        float denom = ((iar + jar[wq]) - inter) + 1e-8f;
        u64 cand = __ballot((double)inter > CMULT * (double)denom);
        accLo[wq] = sel ? (u32)(cand & 0xffffffffu) : accLo[wq];
        accHi[wq] = sel ? (u32)(cand >> 32) : accHi[wq];
      }
    }
    u64* dst = mat + ((size_t)(gp * NN + rb * 64 + lane)) * 128 + jb * 8;
    uint4* d4 = (uint4*)dst;
    d4[0] = make_uint4(accLo[0], accHi[0], accLo[1], accHi[1]);
    d4[1] = make_uint4(accLo[2], accHi[2], accLo[3], accHi[3]);
    d4[2] = make_uint4(accLo[4], accHi[4], accLo[5], accHi[5]);
    d4[3] = make_uint4(accLo[6], accHi[6], accLo[7], accHi[7]);
  }
}

__global__ __launch_bounds__(1024) void scan_kernel(
    const u64* __restrict__ mat, const u64* __restrict__ valid,
    const u32* __restrict__ skey, u64* __restrict__ alive_out,
    u32* __restrict__ kept_key, u32* __restrict__ kept_pos,
    u32* __restrict__ kept_cnt, const u32* __restrict__ flags, int g0)
{
  const int gp = blockIdx.x, g = g0 + gp;
  if (flags[g]) return;
  const int tid = threadIdx.x;
  const int wv = tid >> 6, lane = tid & 63;
  const int wl = tid & 127, grp = tid >> 7;
  __shared__ u64 remv[128];
  __shared__ u64 keepw[128];
  __shared__ u64 keepS;
  __shared__ u32 prefixL[128];

  if (tid < 128) remv[tid] = ~valid[g * 128 + tid];
  __syncthreads();

  const u64* __restrict__ pm = mat + (size_t)gp * NN * 128;
  u64 rwDiag = 0, rwDiagNext = 0;
  if (wv == 0) rwDiag = pm[((size_t)lane) * 128 + 0];

  for (int cc = 0; cc < 128; ++cc) {
    const int w = cc + 1 + wl;
    const bool act = (w < 128);
    u64 rw[8];
    if (act) {
#pragma unroll
      for (int k = 0; k < 8; ++k)
        rw[k] = pm[((size_t)(cc * 64 + grp * 8 + k)) * 128 + w];
    }
    if (wv == 0) {
      u64 m = ~remv[cc];
      u64 keepm = 0;
      while (m) {
        int bp = __ffsll(m) - 1;
        keepm |= 1ull << bp;
        m &= ~(1ull << bp);
        u32 rlo = (u32)__builtin_amdgcn_readlane((int)(u32)(rwDiag & 0xffffffffu), bp);
        u32 rhi = (u32)__builtin_amdgcn_readlane((int)(u32)(rwDiag >> 32), bp);
        m &= ~(((u64)rhi << 32) | rlo);
      }
      if (lane == 0) { keepw[cc] = keepm; keepS = keepm; }
      if (cc + 1 < 128) rwDiagNext = pm[((size_t)((cc + 1) * 64 + lane)) * 128 + (cc + 1)];
    }
    __syncthreads();
    if (act) {
      const u32 kmg = (u32)((keepS >> (grp * 8)) & 0xffu);
      u64 acc = 0;
#pragma unroll
      for (int k = 0; k < 8; ++k)
        if ((kmg >> k) & 1u) acc |= rw[k];
      if (acc) atomicOr(&remv[w], acc);
    }
    if (wv == 0) rwDiag = rwDiagNext;
    __syncthreads();
  }

  if (tid == 0) {
    u32 acc = 0;
    for (int i = 0; i < 128; ++i) { prefixL[i] = acc; acc += (u32)__popcll(keepw[i]); }
    kept_cnt[g] = acc;
  }
  __syncthreads();
  if (tid < 128) alive_out[g * 128 + tid] = keepw[tid];
  for (int p = tid; p < NN; p += 1024) {
    int wd = p >> 6;
    u64 kw = keepw[wd];
    if ((kw >> (p & 63)) & 1ull) {
      u32 rank = prefixL[wd] + (u32)__popcll(kw & ((1ull << (p & 63)) - 1ull));
      if (rank < KEEP_CAP) {
        kept_key[g * KEEP_CAP + rank] = skey[g * NN + p];
        kept_pos[g * KEEP_CAP + rank] = (u32)p;
      }
    }
  }
}

// ================= old path (fallback when ws too small, r2) ==============
__global__ __launch_bounds__(1024) void nms_kernel(
    const float* __restrict__ in, u32* __restrict__ sorted_orig,
    u64* __restrict__ alive_out, u32* __restrict__ kept_key,
    u32* __restrict__ kept_pos, u32* __restrict__ kept_cnt)
{
  const int g = blockIdx.x;
  const int b = g / NC, c = g % NC;
  const float* __restrict__ base = in + (size_t)b * NN * 11;
  __shared__ u32 keys[NN];
  __shared__ uint16_t sidx[NN];
  __shared__ float4 keeperBuf[2][64];
  __shared__ int nkBuf[2];
  __shared__ u64 aliveArr[128];
  __shared__ u32 prefix[128];
  const int tid = threadIdx.x;
  const int w = tid >> 6, lane = tid & 63;

  for (int p = tid; p < NN; p += 1024) {
    float sc = base[p * 11 + 7 + c];
    float s = (sc > 0.1f) ? sc : -INFINITY;
    keys[p] = sort_key(s);
    sidx[p] = (uint16_t)p;
  }
  __syncthreads();
  for (int k = 2; k <= NN; k <<= 1) {
    for (int j = k >> 1; j > 0; j >>= 1) {
      for (int t = tid; t < NN / 2; t += 1024) {
        int i = (t << 1) - (t & (j - 1));
        int q = i | j;
        u32 ka = keys[i], kb = keys[q];
        uint16_t ia = sidx[i], ib = sidx[q];
        bool gt = (ka > kb) || (ka == kb && ia > ib);
        bool up = ((i & k) == 0);
        if (gt == up) { keys[i] = kb; keys[q] = ka; sidx[i] = ib; sidx[q] = ia; }
      }
      __syncthreads();
    }
  }
  float bx1[8], by1[8], bx2[8], by2[8], barea[8];
  u64 alive[8];
#pragma unroll
  for (int k = 0; k < 8; ++k) {
    int p = k * 1024 + tid;
    u32 key = keys[p];
    int orig = sidx[p];
    sorted_orig[g * NN + p] = (u32)orig;
    const float* r = base + orig * 11;
    float x = r[0], y = r[1], l = r[3], wd = r[4];
    float hx = l * 0.5f, hy = wd * 0.5f;
    bx1[k] = x - hx; by1[k] = y - hy; bx2[k] = x + hx; by2[k] = y + hy;
    barea[k] = (bx2[k] - bx1[k]) * (by2[k] - by1[k]);
    alive[k] = __ballot(key != 0xFF800000u);
  }
  for (int cc = 0; cc < 128; ++cc) {
    __syncthreads();
    int nk_prev = (cc > 0) ? nkBuf[(cc - 1) & 1] : 0;
    if (nk_prev > 0) {
      const int par = (cc - 1) & 1;
      for (int j = 0; j < nk_prev; ++j) {
        float4 K = keeperBuf[par][j];
        float ka = (K.z - K.x) * (K.w - K.y);
#pragma unroll
        for (int k = 0; k < 8; ++k) {
          if ((k * 16 + w) < cc) continue;
          if (alive[k] == 0ull) continue;
          float iw = fminf(bx2[k], K.z) - fmaxf(bx1[k], K.x);
          float ih = fminf(by2[k], K.w) - fmaxf(by1[k], K.y);
          iw = fmaxf(iw, 0.0f); ih = fmaxf(ih, 0.0f);
          float inter = iw * ih;
          float denom = (barea[k] + ka) - inter + 1e-8f;
          float t = 0.25f * denom;
          u64 sup = __ballot(inter > t);
          u64 wnd = __ballot(inter > t && inter <= t * NMS_EPS);
          if (wnd) {
            bool bb = inter > t;
            if (bb && inter <= t * NMS_EPS) bb = (inter / denom) > 0.25f;
            sup = __ballot(bb);
          }
          alive[k] &= ~sup;
        }
      }
    }
    if (w == (cc & 15)) {
      float mx1 = 0.f, my1 = 0.f, mx2 = 0.f, my2 = 0.f, ma = 0.f;
      u64 m = 0ull;
#pragma unroll
      for (int k = 0; k < 8; ++k) if (k == (cc >> 4)) {
        mx1 = bx1[k]; my1 = by1[k]; mx2 = bx2[k]; my2 = by2[k]; ma = barea[k];
        m = alive[k];
      }
      u64 keepm = 0ull;
      int nk = 0;
      while (m) {
        int bp = __ffsll(m) - 1;
        keepm |= 1ull << bp;
        m &= ~(1ull << bp);
        float kx1 = __shfl(mx1, bp), ky1 = __shfl(my1, bp);
        float kx2 = __shfl(mx2, bp), ky2 = __shfl(my2, bp);
        float ka = (kx2 - kx1) * (ky2 - ky1);
        float iw = fminf(mx2, kx2) - fmaxf(mx1, kx1);
        float ih = fminf(my2, ky2) - fmaxf(my1, ky1);
        iw = fmaxf(iw, 0.0f); ih = fmaxf(ih, 0.0f);
        float inter = iw * ih;
        float denom = (ma + ka) - inter + 1e-8f;
        float t = 0.25f * denom;
        u64 sup = __ballot(inter > t);
        u64 wnd = __ballot(inter > t && inter <= t * NMS_EPS);
        if (wnd) {
          bool bb = inter > t;
          if (bb && inter <= t * NMS_EPS) bb = (inter / denom) > 0.25f;
          sup = __ballot(bb);
        }
        m &= ~sup;
        if (lane == bp) keeperBuf[cc & 1][nk] = make_float4(mx1, my1, mx2, my2);
        nk++;
      }
#pragma unroll
      for (int k = 0; k < 8; ++k) if (k == (cc >> 4)) alive[k] = keepm;
      if (lane == 0) nkBuf[cc & 1] = nk;
    }
  }
  __syncthreads();
  if (lane == 0) {
#pragma unroll
    for (int k = 0; k < 8; ++k) aliveArr[k * 16 + w] = alive[k];
  }
  __syncthreads();
  if (tid == 0) {
    u32 acc = 0;
    for (int i = 0; i < 128; ++i) { prefix[i] = acc; acc += (u32)__popcll(aliveArr[i]); }
    kept_cnt[g] = acc;
  }
  __syncthreads();
  for (int i = tid; i < 128; i += 1024) alive_out[g * 128 + i] = aliveArr[i];
#pragma unroll
  for (int k = 0; k < 8; ++k) {
    int word = k * 16 + w;
    u64 a = alive[k];
    if ((a >> lane) & 1ull) {
      u32 rank = prefix[word] + (u32)__popcll(a & ((1ull << lane) - 1ull));
      if (rank < KEEP_CAP) {
        int p = k * 1024 + tid;
        kept_key[g * KEEP_CAP + rank] = keys[p];
        kept_pos[g * KEEP_CAP + rank] = (u32)p;
      }
    }
  }
}

// ============ top-k via 3-way sorted-list merge (no bitonic) ===============
__global__ __launch_bounds__(512) void topk_kernel(
    const float* __restrict__ in, const u32* __restrict__ sorted_orig,
    const u64* __restrict__ alive_ws, const u32* __restrict__ kept_key,
    const u32* __restrict__ kept_pos, const u32* __restrict__ kept_cnt,
    float* __restrict__ out)
{
  const int b = blockIdx.x;
  const int tid = threadIdx.x;
  __shared__ u64 arr[NC][KEEP_CAP];
  __shared__ int sT[3], sL[3];
  if (tid < 3) {
    int K = (int)kept_cnt[b * 3 + tid];
    sT[tid] = K;
    sL[tid] = min(K, KEEP_CAP);
  }
  __syncthreads();
  const int L0 = sL[0], L1 = sL[1], L2 = sL[2];
  const int navail = L0 + L1 + L2;
  const int Ttot = sT[0] + sT[1] + sT[2];

  for (int s = tid; s < NC * KEEP_CAP; s += 512) {
    int c = s >> 9, i = s & 511;
    u64 key = ~0ull;
    if (i < sL[c]) {
      int g = b * 3 + c;
      u64 k32 = kept_key[g * KEEP_CAP + i];
      u32 pos = kept_pos[g * KEEP_CAP + i];
      key = (k32 << 15) | (u32)(c * NN + pos);
    }
    arr[c][i] = key;
  }
  __syncthreads();

  // each valid element: global rank = own index + lower_bounds in other lists
  for (int s = tid; s < NC * KEEP_CAP; s += 512) {
    int c = s >> 9, i = s & 511;
    if (i >= sL[c]) continue;
    u64 k = arr[c][i];
    int rank = i;
#pragma unroll
    for (int oc = 0; oc < NC; ++oc) {
      if (oc == c) continue;
      int lo = 0, hi = sL[oc];
      while (lo < hi) { int mid = (lo + hi) >> 1; if (arr[oc][mid] < k) lo = mid + 1; else hi = mid; }
      rank += lo;
    }
    if (rank < MAXN) {
      u32 flat = (u32)(k & 32767u);
      int cc = (int)(flat >> 13), pos = (int)(flat & 8191);
      u32 k32 = (u32)(k >> 15);
      u32 o = ~k32;
      u32 bits = (o & 0x80000000u) ? (o ^ 0x80000000u) : ~o;
      float sval = __uint_as_float(bits);
      u32 orig = sorted_orig[(b * 3 + cc) * NN + pos];
      const float* row = in + ((size_t)b * NN + orig) * 11;
      const float PI_F = 3.14159265358979323846f;
      float theta = row[6];
      float v = theta / PI_F;
      float fl = floorf(v + 1.0f);
      float lp = theta - fl * PI_F;
      float ang = lp + (1.0f - row[10]) * PI_F;
      float* ob = out + ((size_t)b * MAXN + rank) * 7;
      ob[0] = row[0]; ob[1] = row[1]; ob[2] = row[2];
      ob[3] = row[3]; ob[4] = row[4]; ob[5] = row[5]; ob[6] = ang;
      out[NB * MAXN * 7 + b * MAXN + rank] = (float)cc;
      out[NB * MAXN * 7 + NB * MAXN + b * MAXN + rank] = sval;
    }
  }

  // fallback rows [navail, MAXN): (r-Ttot)-th non-kept flat index, -inf score
  for (int r = navail + tid; r < MAXN; r += 512) {
    int need = r - Ttot;
    int fflat = 0;
    for (int wd = 0; wd < 384; ++wd) {
      u64 a = alive_ws[b * 384 + wd];
      int z = 64 - __popcll(a);
      if (need < z) {
        u64 na = ~a;
        for (int it = 0; it < need; ++it) na &= na - 1ull;
        fflat = wd * 64 + (__ffsll(na) - 1);
        break;
      }
      need -= z;
    }
    int c = fflat >> 13, pos = fflat & 8191;
    u32 orig = sorted_orig[(b * 3 + c) * NN + pos];
    const float* row = in + ((size_t)b * NN + orig) * 11;
    const float PI_F = 3.14159265358979323846f;
    float theta = row[6];
    float v = theta / PI_F;
    float fl = floorf(v + 1.0f);
    float lp = theta - fl * PI_F;
    float ang = lp + (1.0f - row[10]) * PI_F;
    float* ob = out + ((size_t)b * MAXN + r) * 7;
    ob[0] = row[0]; ob[1] = row[1]; ob[2] = row[2];
    ob[3] = row[3]; ob[4] = row[4]; ob[5] = row[5]; ob[6] = ang;
    out[NB * MAXN * 7 + b * MAXN + r] = (float)c;
    out[NB * MAXN * 7 + NB * MAXN + b * MAXN + r] = -INFINITY;
  }
}

extern "C" void kernel_launch(void* const* d_in, const int* in_sizes, int n_in,
                              void* d_out, int out_size, void* d_ws, size_t ws_size,
                              hipStream_t stream) {
  const float* in = (const float*)d_in[0];
  float* out = (float*)d_out;
  char* ws = (char*)d_ws;

  int P = 0;
  const int cands[6] = {12, 6, 4, 3, 2, 1};
  for (int ci = 0; ci < 6; ++ci) {
    if ((size_t)NMAT + (size_t)cands[ci] * MATB <= ws_size) { P = cands[ci]; break; }
  }

  if (P > 0) {
    u32* so = (u32*)(ws + NSO);
    u32* skey = (u32*)(ws + NSKEY);
    float4* sb4 = (float4*)(ws + NSB4);
    float* sar = (float*)(ws + NSAR);
    u64* valid = (u64*)(ws + NVAL);
    u64* alive = (u64*)(ws + NALV);
    u32* kkey = (u32*)(ws + NKKEY);
    u32* kpos = (u32*)(ws + NKPOS);
    u32* kcnt = (u32*)(ws + NKCNT);
    u32* flags = (u32*)(ws + NFLG);
    u64* pmat = (u64*)(ws + PMAT);
    u64* kk = (u64*)(ws + PMAT);        // alias: dead before build_prefix runs
    u64* mat = (u64*)(ws + NMAT);

    sortL_kernel<<<dim3(48), dim3(256), 0, stream>>>(in, kk);
    sortX1_kernel<<<dim3(24), dim3(512), 0, stream>>>(kk);
    sortX2_kernel<<<dim3(48), dim3(1024), 0, stream>>>(kk);
    sortX3_kernel<<<dim3(24), dim3(512), 0, stream>>>(
        in, kk, so, skey, sb4, sar, valid);
    build_prefix_kernel<<<dim3(PB_BLOCKS), dim3(PB_TPB), 0, stream>>>(
        sb4, sar, pmat);
    scan_prefix_kernel<<<dim3(NG), dim3(1024), 0, stream>>>(
        pmat, valid, skey, kkey, kpos, kcnt, flags);
    for (int g0 = 0; g0 < NG; g0 += P) {
      build_kernel<<<dim3(BUILD_BLOCKS), dim3(BUILD_TPB), 0, stream>>>(
          sb4, sar, mat, flags, g0, P);
      scan_kernel<<<dim3(P), dim3(1024), 0, stream>>>(
          mat, valid, skey, alive, kkey, kpos, kcnt, flags, g0);
    }
    topk_kernel<<<dim3(NB), dim3(512), 0, stream>>>(
        in, so, alive, kkey, kpos, kcnt, out);
  } else {
    u32* sorted_orig = (u32*)(ws + WS_SORTED_ORIG);
    u64* alive = (u64*)(ws + WS_ALIVE);
    u32* kept_key = (u32*)(ws + WS_KEPT_KEY);
    u32* kept_pos = (u32*)(ws + WS_KEPT_POS);
    u32* kept_cnt = (u32*)(ws + WS_KEPT_CNT);
    nms_kernel<<<dim3(NG), dim3(1024), 0, stream>>>(
        in, sorted_orig, alive, kept_key, kept_pos, kept_cnt);
    topk_kernel<<<dim3(NB), dim3(512), 0, stream>>>(
        in, sorted_orig, alive, kept_key, kept_pos, kept_cnt, out);
  }
}